// Round 1
// baseline (4942.606 us; speedup 1.0000x reference)
//
#include <hip/hip_runtime.h>

#define IN_F 128
#define HIDC 16
#define NHEAD 8
#define HHID 128   // NHEAD*HIDC
#define EDIM 8

// ---------------------------------------------------------------------------
// wcomb[h*8+d] = sum_c att_edge[h,c] * lin_edge_w[h*16+c, d]
__global__ __launch_bounds__(64) void k_wcomb(const float* __restrict__ att_edge,
                                              const float* __restrict__ lin_edge_w,
                                              float* __restrict__ wcomb) {
    int t = threadIdx.x;
    if (t < 64) {
        int h = t >> 3, d = t & 7;
        float s = 0.f;
        #pragma unroll
        for (int c = 0; c < HIDC; ++c)
            s += att_edge[h * HIDC + c] * lin_edge_w[(h * HIDC + c) * EDIM + d];
        wcomb[t] = s;
    }
}

// ---------------------------------------------------------------------------
// Per node: h = x@fc_w.T + fc_b ; xp = h@lin_w.T ; a_src/a_dst dots.
__global__ __launch_bounds__(128) void k_node(const float* __restrict__ x,
                                              const float* __restrict__ fc_w,
                                              const float* __restrict__ fc_b,
                                              const float* __restrict__ lin_w,
                                              const float* __restrict__ att_src,
                                              const float* __restrict__ att_dst,
                                              float* __restrict__ xp,
                                              float* __restrict__ a_src,
                                              float* __restrict__ a_dst,
                                              int N) {
    __shared__ float s_fc[HIDC * IN_F];    // [16][128]
    __shared__ float s_lin[HHID * HIDC];   // [128][16]
    __shared__ float s_as[HHID], s_ad[HHID], s_fcb[HIDC];
    int t = threadIdx.x;
    for (int i = t; i < HIDC * IN_F; i += 128) s_fc[i] = fc_w[i];
    for (int i = t; i < HHID * HIDC; i += 128) s_lin[i] = lin_w[i];
    if (t < HHID) { s_as[t] = att_src[t]; s_ad[t] = att_dst[t]; }
    if (t < HIDC) s_fcb[t] = fc_b[t];
    __syncthreads();

    int n = blockIdx.x * 128 + t;
    if (n >= N) return;

    float h[HIDC];
    #pragma unroll
    for (int k = 0; k < HIDC; ++k) h[k] = s_fcb[k];
    const float* xr = x + (size_t)n * IN_F;
    for (int d = 0; d < IN_F; ++d) {
        float xv = xr[d];
        #pragma unroll
        for (int k = 0; k < HIDC; ++k) h[k] += xv * s_fc[k * IN_F + d];
    }

    float* xpr = xp + (size_t)n * HHID;
    for (int hh = 0; hh < NHEAD; ++hh) {
        float as = 0.f, ad = 0.f;
        #pragma unroll
        for (int c = 0; c < HIDC; ++c) {
            int j = hh * HIDC + c;
            float v = 0.f;
            #pragma unroll
            for (int k = 0; k < HIDC; ++k) v += h[k] * s_lin[j * HIDC + k];
            xpr[j] = v;
            as += v * s_as[j];
            ad += v * s_ad[j];
        }
        a_src[n * NHEAD + hh] = as;
        a_dst[n * NHEAD + hh] = ad;
    }
}

// ---------------------------------------------------------------------------
// Per edge: logits -> LeakyReLU -> exp ; atomic denom accumulate.
__global__ __launch_bounds__(256) void k_edge(const float* __restrict__ ea,
                                              const int* __restrict__ ei,
                                              const float* __restrict__ a_src,
                                              const float* __restrict__ a_dst,
                                              const float* __restrict__ wcomb,
                                              float* __restrict__ exb,
                                              float* __restrict__ denom,
                                              int E) {
    __shared__ float s_w[64];
    int t = threadIdx.x;
    if (t < 64) s_w[t] = wcomb[t];
    __syncthreads();
    int e = blockIdx.x * 256 + t;
    if (e >= E) return;

    int s = ei[e];
    int d = ei[E + e];

    float4 ea0 = *(const float4*)(ea + (size_t)e * EDIM);
    float4 ea1 = *(const float4*)(ea + (size_t)e * EDIM + 4);
    float eav[8] = {ea0.x, ea0.y, ea0.z, ea0.w, ea1.x, ea1.y, ea1.z, ea1.w};

    float4 as0 = *(const float4*)(a_src + (size_t)s * NHEAD);
    float4 as1 = *(const float4*)(a_src + (size_t)s * NHEAD + 4);
    float4 ad0 = *(const float4*)(a_dst + (size_t)d * NHEAD);
    float4 ad1 = *(const float4*)(a_dst + (size_t)d * NHEAD + 4);
    float asv[8] = {as0.x, as0.y, as0.z, as0.w, as1.x, as1.y, as1.z, as1.w};
    float adv[8] = {ad0.x, ad0.y, ad0.z, ad0.w, ad1.x, ad1.y, ad1.z, ad1.w};

    float exs[8];
    #pragma unroll
    for (int h = 0; h < NHEAD; ++h) {
        float aev = 0.f;
        #pragma unroll
        for (int dd = 0; dd < EDIM; ++dd) aev += eav[dd] * s_w[h * EDIM + dd];
        float lg = asv[h] + adv[h] + aev;
        lg = (lg >= 0.f) ? lg : 0.2f * lg;
        float ev = __expf(lg);
        exs[h] = ev;
        atomicAdd(&denom[d * NHEAD + h], ev);
    }
    *(float4*)(exb + (size_t)e * NHEAD)     = make_float4(exs[0], exs[1], exs[2], exs[3]);
    *(float4*)(exb + (size_t)e * NHEAD + 4) = make_float4(exs[4], exs[5], exs[6], exs[7]);
}

// ---------------------------------------------------------------------------
// Per (edge, head): alpha = ex/denom ; agg[dst,h,:] += alpha * xp[src,h,:]
__global__ __launch_bounds__(256) void k_scatter(const float* __restrict__ exb,
                                                 const float* __restrict__ denom,
                                                 const int* __restrict__ ei,
                                                 const float* __restrict__ xp,
                                                 float* __restrict__ agg,
                                                 float* __restrict__ attn66,
                                                 int E) {
    int t = threadIdx.x;
    int e = blockIdx.x * 32 + (t >> 3);
    int h = t & 7;
    if (e >= E) return;
    int s = ei[e];
    int d = ei[E + e];
    float ev = exb[(size_t)e * NHEAD + h];
    float dn = denom[d * NHEAD + h];
    float alpha = ev / (dn + 1e-16f);
    if (h == 0 && s == 6 && d == 6) atomicAdd(attn66, alpha);

    const float* xr = xp + (size_t)s * HHID + h * HIDC;
    float* ar = agg + (size_t)d * HHID + h * HIDC;
    float4 v0 = *(const float4*)(xr + 0);
    float4 v1 = *(const float4*)(xr + 4);
    float4 v2 = *(const float4*)(xr + 8);
    float4 v3 = *(const float4*)(xr + 12);
    atomicAdd(ar + 0,  alpha * v0.x); atomicAdd(ar + 1,  alpha * v0.y);
    atomicAdd(ar + 2,  alpha * v0.z); atomicAdd(ar + 3,  alpha * v0.w);
    atomicAdd(ar + 4,  alpha * v1.x); atomicAdd(ar + 5,  alpha * v1.y);
    atomicAdd(ar + 6,  alpha * v1.z); atomicAdd(ar + 7,  alpha * v1.w);
    atomicAdd(ar + 8,  alpha * v2.x); atomicAdd(ar + 9,  alpha * v2.y);
    atomicAdd(ar + 10, alpha * v2.z); atomicAdd(ar + 11, alpha * v2.w);
    atomicAdd(ar + 12, alpha * v3.x); atomicAdd(ar + 13, alpha * v3.y);
    atomicAdd(ar + 14, alpha * v3.z); atomicAdd(ar + 15, alpha * v3.w);
}

// ---------------------------------------------------------------------------
// Per node: head-mean + bias + ELU ; attention score.
__global__ __launch_bounds__(256) void k_nodeout(const float* __restrict__ agg,
                                                 const float* __restrict__ conv_bias,
                                                 const float* __restrict__ attn_w,
                                                 const float* __restrict__ attn_b,
                                                 float* __restrict__ out_feat,
                                                 float* __restrict__ score,
                                                 int N) {
    int n = blockIdx.x * 256 + threadIdx.x;
    if (n >= N) return;
    const float* ar = agg + (size_t)n * HHID;
    float sc = 0.f;
    #pragma unroll
    for (int c = 0; c < HIDC; ++c) {
        float s = 0.f;
        #pragma unroll
        for (int h = 0; h < NHEAD; ++h) s += ar[h * HIDC + c];
        float v = s * 0.125f + conv_bias[c];
        v = (v > 0.f) ? v : (expm1f(v));
        out_feat[n * HIDC + c] = v;
        sc += v * attn_w[c];
    }
    score[n] = sc + attn_b[0];
}

// ---------------------------------------------------------------------------
// Single block: node-softmax stats; also seed d_out with bias + attn66.
__global__ __launch_bounds__(1024) void k_reduce(const float* __restrict__ score,
                                                 int N, float* __restrict__ red,
                                                 const float* __restrict__ out_b,
                                                 const float* __restrict__ attn66,
                                                 float* __restrict__ d_out) {
    __shared__ float sm[1024];
    int t = threadIdx.x;
    float mx = -1e30f;
    for (int i = t; i < N; i += 1024) mx = fmaxf(mx, score[i]);
    sm[t] = mx; __syncthreads();
    for (int s2 = 512; s2 > 0; s2 >>= 1) {
        if (t < s2) sm[t] = fmaxf(sm[t], sm[t + s2]);
        __syncthreads();
    }
    mx = sm[0]; __syncthreads();
    float se = 0.f;
    for (int i = t; i < N; i += 1024) se += __expf(score[i] - mx);
    sm[t] = se; __syncthreads();
    for (int s2 = 512; s2 > 0; s2 >>= 1) {
        if (t < s2) sm[t] += sm[t + s2];
        __syncthreads();
    }
    if (t == 0) { red[0] = mx; red[1] = sm[0]; }
    if (t < 3) d_out[t] = out_b[t];
    if (t == 3) d_out[3] = attn66[0];
}

// ---------------------------------------------------------------------------
// y[o] += sum_i (out_feat[i]*w[n]) * out_w[o*N*16 + i]
__global__ __launch_bounds__(256) void k_final(const float* __restrict__ out_feat,
                                               const float* __restrict__ score,
                                               const float* __restrict__ red,
                                               const float* __restrict__ out_w,
                                               float* __restrict__ d_out,
                                               int N) {
    float mx = red[0];
    float inv_se = 1.0f / red[1];
    int total = N * HIDC;
    float p0 = 0.f, p1 = 0.f, p2 = 0.f;
    for (int i = blockIdx.x * blockDim.x + threadIdx.x; i < total;
         i += gridDim.x * blockDim.x) {
        int n = i >> 4;
        float w = __expf(score[n] - mx) * inv_se;
        float f = out_feat[i] * w;
        p0 += f * out_w[i];
        p1 += f * out_w[total + i];
        p2 += f * out_w[2 * total + i];
    }
    #pragma unroll
    for (int off = 32; off > 0; off >>= 1) {
        p0 += __shfl_down(p0, off);
        p1 += __shfl_down(p1, off);
        p2 += __shfl_down(p2, off);
    }
    if ((threadIdx.x & 63) == 0) {
        atomicAdd(&d_out[0], p0);
        atomicAdd(&d_out[1], p1);
        atomicAdd(&d_out[2], p2);
    }
}

// ---------------------------------------------------------------------------
extern "C" void kernel_launch(void* const* d_in, const int* in_sizes, int n_in,
                              void* d_out, int out_size, void* d_ws, size_t ws_size,
                              hipStream_t stream) {
    const float* x          = (const float*)d_in[0];
    const float* edge_attr  = (const float*)d_in[1];
    const float* fc_w       = (const float*)d_in[2];
    const float* fc_b       = (const float*)d_in[3];
    const float* lin_w      = (const float*)d_in[4];
    const float* att_src    = (const float*)d_in[5];
    const float* att_dst    = (const float*)d_in[6];
    const float* att_edge   = (const float*)d_in[7];
    const float* lin_edge_w = (const float*)d_in[8];
    const float* conv_bias  = (const float*)d_in[9];
    const float* attn_fc_w  = (const float*)d_in[10];
    const float* attn_fc_b  = (const float*)d_in[11];
    const float* out_w      = (const float*)d_in[12];
    const float* out_b      = (const float*)d_in[13];
    const int*   edge_index = (const int*)d_in[14];
    float* out = (float*)d_out;

    const int N = in_sizes[0] / IN_F;
    const int E = in_sizes[14] / 2;

    // workspace layout (floats)
    float* ws = (float*)d_ws;
    size_t off = 0;
    float* xp       = ws + off; off += (size_t)N * HHID;   // 1,280,000
    float* a_src    = ws + off; off += (size_t)N * NHEAD;  //    80,000
    float* a_dst    = ws + off; off += (size_t)N * NHEAD;  //    80,000
    float* exb      = ws + off; off += (size_t)E * NHEAD;  // 5,120,000
    float* out_feat = ws + off; off += (size_t)N * HIDC;   //   160,000
    float* score    = ws + off; off += (size_t)N;          //    10,000
    float* wcomb    = ws + off; off += 64;
    // ---- zero region start ----
    float* denom    = ws + off; off += (size_t)N * NHEAD;  //    80,000
    float* agg      = ws + off; off += (size_t)N * HHID;   // 1,280,000
    float* attn66   = ws + off; off += 1;
    size_t zero_bytes = ((size_t)N * NHEAD + (size_t)N * HHID + 1) * sizeof(float);
    // ---- zero region end ----
    float* red      = ws + off; off += 2;

    hipMemsetAsync(denom, 0, zero_bytes, stream);

    k_wcomb<<<1, 64, 0, stream>>>(att_edge, lin_edge_w, wcomb);
    k_node<<<(N + 127) / 128, 128, 0, stream>>>(x, fc_w, fc_b, lin_w, att_src, att_dst,
                                                xp, a_src, a_dst, N);
    k_edge<<<(E + 255) / 256, 256, 0, stream>>>(edge_attr, edge_index, a_src, a_dst,
                                                wcomb, exb, denom, E);
    k_scatter<<<(E + 31) / 32, 256, 0, stream>>>(exb, denom, edge_index, xp, agg,
                                                 attn66, E);
    k_nodeout<<<(N + 255) / 256, 256, 0, stream>>>(agg, conv_bias, attn_fc_w, attn_fc_b,
                                                   out_feat, score, N);
    k_reduce<<<1, 1024, 0, stream>>>(score, N, red, out_b, attn66, out);
    k_final<<<256, 256, 0, stream>>>(out_feat, score, red, out_w, out, N);
}

// Round 2
// 284.538 us; speedup vs baseline: 17.3706x; 17.3706x over previous
//
#include <hip/hip_runtime.h>

#define IN_F 128
#define HIDC 16
#define NHEAD 8
#define HHID 128   // NHEAD*HIDC
#define EDIM 8

// ---------------------------------------------------------------------------
// wcomb[h*8+d] = sum_c att_edge[h,c] * lin_edge_w[h*16+c, d]
__global__ __launch_bounds__(64) void k_wcomb(const float* __restrict__ att_edge,
                                              const float* __restrict__ lin_edge_w,
                                              float* __restrict__ wcomb) {
    int t = threadIdx.x;
    int h = t >> 3, d = t & 7;
    float s = 0.f;
    #pragma unroll
    for (int c = 0; c < HIDC; ++c)
        s += att_edge[h * HIDC + c] * lin_edge_w[(h * HIDC + c) * EDIM + d];
    wcomb[t] = s;
}

// ---------------------------------------------------------------------------
// Per node: h = x@fc_w.T + fc_b ; xp = h@lin_w.T ; a_src/a_dst dots.
__global__ __launch_bounds__(128) void k_node(const float* __restrict__ x,
                                              const float* __restrict__ fc_w,
                                              const float* __restrict__ fc_b,
                                              const float* __restrict__ lin_w,
                                              const float* __restrict__ att_src,
                                              const float* __restrict__ att_dst,
                                              float* __restrict__ xp,
                                              float* __restrict__ a_src,
                                              float* __restrict__ a_dst,
                                              int N) {
    __shared__ float s_fc[HIDC * IN_F];    // [16][128]
    __shared__ float s_lin[HHID * HIDC];   // [128][16]
    __shared__ float s_as[HHID], s_ad[HHID], s_fcb[HIDC];
    int t = threadIdx.x;
    for (int i = t; i < HIDC * IN_F; i += 128) s_fc[i] = fc_w[i];
    for (int i = t; i < HHID * HIDC; i += 128) s_lin[i] = lin_w[i];
    if (t < HHID) { s_as[t] = att_src[t]; s_ad[t] = att_dst[t]; }
    if (t < HIDC) s_fcb[t] = fc_b[t];
    __syncthreads();

    int n = blockIdx.x * 128 + t;
    if (n >= N) return;

    float h[HIDC];
    #pragma unroll
    for (int k = 0; k < HIDC; ++k) h[k] = s_fcb[k];
    const float* xr = x + (size_t)n * IN_F;
    for (int d = 0; d < IN_F; ++d) {
        float xv = xr[d];
        #pragma unroll
        for (int k = 0; k < HIDC; ++k) h[k] += xv * s_fc[k * IN_F + d];
    }

    float* xpr = xp + (size_t)n * HHID;
    for (int hh = 0; hh < NHEAD; ++hh) {
        float as = 0.f, ad = 0.f;
        #pragma unroll
        for (int c = 0; c < HIDC; ++c) {
            int j = hh * HIDC + c;
            float v = 0.f;
            #pragma unroll
            for (int k = 0; k < HIDC; ++k) v += h[k] * s_lin[j * HIDC + k];
            xpr[j] = v;
            as += v * s_as[j];
            ad += v * s_ad[j];
        }
        a_src[n * NHEAD + hh] = as;
        a_dst[n * NHEAD + hh] = ad;
    }
}

// ---------------------------------------------------------------------------
// In-degree count (int atomics, L2-resident 40 KB target).
__global__ __launch_bounds__(256) void k_deg(const int* __restrict__ ei,
                                             int* __restrict__ deg, int E) {
    int e = blockIdx.x * 256 + threadIdx.x;
    if (e < E) atomicAdd(&deg[ei[E + e]], 1);
}

// ---------------------------------------------------------------------------
// Exclusive prefix sum of deg[0..N) -> start[0..N], single block.
__global__ __launch_bounds__(1024) void k_scan(const int* __restrict__ deg,
                                               int* __restrict__ start, int N) {
    __shared__ int sm[1024];
    int t = threadIdx.x;
    int carry = 0;
    for (int base = 0; base < N; base += 1024) {
        int v = (base + t < N) ? deg[base + t] : 0;
        __syncthreads();
        sm[t] = v;
        __syncthreads();
        for (int off = 1; off < 1024; off <<= 1) {
            int x = (t >= off) ? sm[t - off] : 0;
            __syncthreads();
            sm[t] += x;
            __syncthreads();
        }
        if (base + t < N) start[base + t] = carry + sm[t] - v;
        carry += sm[1023];
    }
    if (t == 0) start[N] = carry;
}

// ---------------------------------------------------------------------------
// Per edge: logits -> LeakyReLU -> exp(logit) (no max-shift needed; logits are
// O(1) so exp never overflows in fp32 and alpha = ex/sum(ex) is identical).
// Also places the edge id into its CSR bucket.
__global__ __launch_bounds__(256) void k_edge_fill(const float* __restrict__ ea,
                                                   const int* __restrict__ ei,
                                                   const float* __restrict__ a_src,
                                                   const float* __restrict__ a_dst,
                                                   const float* __restrict__ wcomb,
                                                   const int* __restrict__ start,
                                                   int* __restrict__ cursor,
                                                   int* __restrict__ csr_eid,
                                                   float* __restrict__ exb,
                                                   int E) {
    __shared__ float s_w[64];
    int t = threadIdx.x;
    if (t < 64) s_w[t] = wcomb[t];
    __syncthreads();
    int e = blockIdx.x * 256 + t;
    if (e >= E) return;

    int s = ei[e];
    int d = ei[E + e];

    int pos = start[d] + atomicAdd(&cursor[d], 1);
    csr_eid[pos] = e;

    float4 ea0 = *(const float4*)(ea + (size_t)e * EDIM);
    float4 ea1 = *(const float4*)(ea + (size_t)e * EDIM + 4);
    float eav[8] = {ea0.x, ea0.y, ea0.z, ea0.w, ea1.x, ea1.y, ea1.z, ea1.w};

    float4 as0 = *(const float4*)(a_src + (size_t)s * NHEAD);
    float4 as1 = *(const float4*)(a_src + (size_t)s * NHEAD + 4);
    float4 ad0 = *(const float4*)(a_dst + (size_t)d * NHEAD);
    float4 ad1 = *(const float4*)(a_dst + (size_t)d * NHEAD + 4);
    float asv[8] = {as0.x, as0.y, as0.z, as0.w, as1.x, as1.y, as1.z, as1.w};
    float adv[8] = {ad0.x, ad0.y, ad0.z, ad0.w, ad1.x, ad1.y, ad1.z, ad1.w};

    float exs[8];
    #pragma unroll
    for (int h = 0; h < NHEAD; ++h) {
        float aev = 0.f;
        #pragma unroll
        for (int dd = 0; dd < EDIM; ++dd) aev += eav[dd] * s_w[h * EDIM + dd];
        float lg = asv[h] + adv[h] + aev;
        lg = (lg >= 0.f) ? lg : 0.2f * lg;
        exs[h] = __expf(lg);
    }
    *(float4*)(exb + (size_t)e * NHEAD)     = make_float4(exs[0], exs[1], exs[2], exs[3]);
    *(float4*)(exb + (size_t)e * NHEAD + 4) = make_float4(exs[4], exs[5], exs[6], exs[7]);
}

// ---------------------------------------------------------------------------
// One block (128 thr) per destination node. Thread t owns component (h,c),
// h = t>>4, c = t&15. Walks the node's CSR bucket in LDS-staged chunks,
// accumulating sum(ev * xp[src]) and per-head denom in registers. Epilogue
// fuses: alpha normalize, head-mean, +bias, ELU, attn score, attn66.
__global__ __launch_bounds__(128) void k_gather(const int* __restrict__ csr_eid,
                                                const int* __restrict__ start,
                                                const int* __restrict__ ei,
                                                const float* __restrict__ exb,
                                                const float* __restrict__ xp,
                                                const float* __restrict__ conv_bias,
                                                const float* __restrict__ attn_w,
                                                const float* __restrict__ attn_b,
                                                float* __restrict__ out_feat,
                                                float* __restrict__ score,
                                                float* __restrict__ attn66,
                                                int N) {
    int n = blockIdx.x;
    int t = threadIdx.x;
    int h = t >> 4;

    __shared__ int s_e[128], s_s[128];
    __shared__ float sred[128];
    __shared__ float sden[NHEAD];

    int s0 = start[n];
    int s1 = start[n + 1];

    float acc = 0.f;
    float den = 0.f;   // valid in lanes with (t&15)==0
    float a66 = 0.f;   // valid in lane 0 of block 6

    for (int base = s0; base < s1; base += 128) {
        int m = s1 - base; if (m > 128) m = 128;
        if (t < m) {
            int e = csr_eid[base + t];
            s_e[t] = e;
            s_s[t] = ei[e];
        }
        __syncthreads();
        for (int i = 0; i < m; ++i) {
            int e = s_e[i];
            int s = s_s[i];
            float ev = exb[(size_t)e * NHEAD + h];
            acc += ev * xp[(size_t)s * HHID + t];
            if ((t & 15) == 0) den += ev;
            if (t == 0 && n == 6 && s == 6) a66 += ev;
        }
        __syncthreads();
    }

    if ((t & 15) == 0) sden[h] = den;
    __syncthreads();
    float inv = 1.f / (sden[h] + 1e-16f);
    acc *= inv;
    if (n == 6 && t == 0) attn66[0] = a66 / (sden[0] + 1e-16f);

    sred[t] = acc;
    __syncthreads();
    if (t < HIDC) {
        float sum = 0.f;
        #pragma unroll
        for (int hh = 0; hh < NHEAD; ++hh) sum += sred[hh * HIDC + t];
        float v = sum * 0.125f + conv_bias[t];
        v = (v > 0.f) ? v : expm1f(v);
        out_feat[n * HIDC + t] = v;
        sred[t] = v * attn_w[t];
    }
    __syncthreads();
    if (t == 0) {
        float sc = 0.f;
        #pragma unroll
        for (int c = 0; c < HIDC; ++c) sc += sred[c];
        score[n] = sc + attn_b[0];
    }
}

// ---------------------------------------------------------------------------
// Single block: node-softmax stats; also seed d_out with bias + attn66.
__global__ __launch_bounds__(1024) void k_reduce(const float* __restrict__ score,
                                                 int N, float* __restrict__ red,
                                                 const float* __restrict__ out_b,
                                                 const float* __restrict__ attn66,
                                                 float* __restrict__ d_out) {
    __shared__ float sm[1024];
    int t = threadIdx.x;
    float mx = -1e30f;
    for (int i = t; i < N; i += 1024) mx = fmaxf(mx, score[i]);
    sm[t] = mx; __syncthreads();
    for (int s2 = 512; s2 > 0; s2 >>= 1) {
        if (t < s2) sm[t] = fmaxf(sm[t], sm[t + s2]);
        __syncthreads();
    }
    mx = sm[0]; __syncthreads();
    float se = 0.f;
    for (int i = t; i < N; i += 1024) se += __expf(score[i] - mx);
    sm[t] = se; __syncthreads();
    for (int s2 = 512; s2 > 0; s2 >>= 1) {
        if (t < s2) sm[t] += sm[t + s2];
        __syncthreads();
    }
    if (t == 0) { red[0] = mx; red[1] = sm[0]; }
    if (t < 3) d_out[t] = out_b[t];
    if (t == 3) d_out[3] = attn66[0];
}

// ---------------------------------------------------------------------------
// y[o] += sum_i (out_feat[i]*w[n]) * out_w[o*N*16 + i]
__global__ __launch_bounds__(256) void k_final(const float* __restrict__ out_feat,
                                               const float* __restrict__ score,
                                               const float* __restrict__ red,
                                               const float* __restrict__ out_w,
                                               float* __restrict__ d_out,
                                               int N) {
    float mx = red[0];
    float inv_se = 1.0f / red[1];
    int total = N * HIDC;
    float p0 = 0.f, p1 = 0.f, p2 = 0.f;
    for (int i = blockIdx.x * blockDim.x + threadIdx.x; i < total;
         i += gridDim.x * blockDim.x) {
        int n = i >> 4;
        float w = __expf(score[n] - mx) * inv_se;
        float f = out_feat[i] * w;
        p0 += f * out_w[i];
        p1 += f * out_w[total + i];
        p2 += f * out_w[2 * total + i];
    }
    #pragma unroll
    for (int off = 32; off > 0; off >>= 1) {
        p0 += __shfl_down(p0, off);
        p1 += __shfl_down(p1, off);
        p2 += __shfl_down(p2, off);
    }
    if ((threadIdx.x & 63) == 0) {
        atomicAdd(&d_out[0], p0);
        atomicAdd(&d_out[1], p1);
        atomicAdd(&d_out[2], p2);
    }
}

// ---------------------------------------------------------------------------
extern "C" void kernel_launch(void* const* d_in, const int* in_sizes, int n_in,
                              void* d_out, int out_size, void* d_ws, size_t ws_size,
                              hipStream_t stream) {
    const float* x          = (const float*)d_in[0];
    const float* edge_attr  = (const float*)d_in[1];
    const float* fc_w       = (const float*)d_in[2];
    const float* fc_b       = (const float*)d_in[3];
    const float* lin_w      = (const float*)d_in[4];
    const float* att_src    = (const float*)d_in[5];
    const float* att_dst    = (const float*)d_in[6];
    const float* att_edge   = (const float*)d_in[7];
    const float* lin_edge_w = (const float*)d_in[8];
    const float* conv_bias  = (const float*)d_in[9];
    const float* attn_fc_w  = (const float*)d_in[10];
    const float* attn_fc_b  = (const float*)d_in[11];
    const float* out_w      = (const float*)d_in[12];
    const float* out_b      = (const float*)d_in[13];
    const int*   edge_index = (const int*)d_in[14];
    float* out = (float*)d_out;

    const int N = in_sizes[0] / IN_F;
    const int E = in_sizes[14] / 2;

    // workspace layout
    float* ws = (float*)d_ws;
    size_t off = 0;
    float* xp       = ws + off; off += (size_t)N * HHID;    // 1,280,000
    float* a_src    = ws + off; off += (size_t)N * NHEAD;   //    80,000
    float* a_dst    = ws + off; off += (size_t)N * NHEAD;   //    80,000
    float* exb      = ws + off; off += (size_t)E * NHEAD;   // 5,120,000
    float* out_feat = ws + off; off += (size_t)N * HIDC;    //   160,000
    float* score    = ws + off; off += (size_t)N;           //    10,000
    float* wcomb    = ws + off; off += 64;
    float* attn66   = ws + off; off += 1;
    float* red      = ws + off; off += 2;
    int* iws = (int*)(ws + off);
    size_t ioff = 0;
    int* deg     = iws + ioff; ioff += N;       // ---- zeroed each call ----
    int* cursor  = iws + ioff; ioff += N;       // ---- zeroed each call ----
    int* start   = iws + ioff; ioff += N + 1;
    int* csr_eid = iws + ioff; ioff += E;

    hipMemsetAsync(deg, 0, 2 * (size_t)N * sizeof(int), stream);

    k_wcomb<<<1, 64, 0, stream>>>(att_edge, lin_edge_w, wcomb);
    k_node<<<(N + 127) / 128, 128, 0, stream>>>(x, fc_w, fc_b, lin_w, att_src, att_dst,
                                                xp, a_src, a_dst, N);
    k_deg<<<(E + 255) / 256, 256, 0, stream>>>(edge_index, deg, E);
    k_scan<<<1, 1024, 0, stream>>>(deg, start, N);
    k_edge_fill<<<(E + 255) / 256, 256, 0, stream>>>(edge_attr, edge_index, a_src, a_dst,
                                                     wcomb, start, cursor, csr_eid,
                                                     exb, E);
    k_gather<<<N, 128, 0, stream>>>(csr_eid, start, edge_index, exb, xp, conv_bias,
                                    attn_fc_w, attn_fc_b, out_feat, score, attn66, N);
    k_reduce<<<1, 1024, 0, stream>>>(score, N, red, out_b, attn66, out);
    k_final<<<256, 256, 0, stream>>>(out_feat, score, red, out_w, out, N);
}

// Round 3
// 219.750 us; speedup vs baseline: 22.4919x; 1.2948x over previous
//
#include <hip/hip_runtime.h>
#include <hip/hip_fp16.h>

#define IN_F 128
#define HIDC 16
#define NHEAD 8
#define HHID 128   // NHEAD*HIDC
#define EDIM 8

// ---------------------------------------------------------------------------
// Per node: h = x@fc_w.T + fc_b ; xp = h@lin_w.T ; a_src/a_dst dots.
__global__ __launch_bounds__(128) void k_node(const float* __restrict__ x,
                                              const float* __restrict__ fc_w,
                                              const float* __restrict__ fc_b,
                                              const float* __restrict__ lin_w,
                                              const float* __restrict__ att_src,
                                              const float* __restrict__ att_dst,
                                              float* __restrict__ xp,
                                              float* __restrict__ a_src,
                                              float* __restrict__ a_dst,
                                              int N) {
    __shared__ float s_fc[HIDC * IN_F];    // [16][128]
    __shared__ float s_lin[HHID * HIDC];   // [128][16]
    __shared__ float s_as[HHID], s_ad[HHID], s_fcb[HIDC];
    int t = threadIdx.x;
    for (int i = t; i < HIDC * IN_F; i += 128) s_fc[i] = fc_w[i];
    for (int i = t; i < HHID * HIDC; i += 128) s_lin[i] = lin_w[i];
    if (t < HHID) { s_as[t] = att_src[t]; s_ad[t] = att_dst[t]; }
    if (t < HIDC) s_fcb[t] = fc_b[t];
    __syncthreads();

    int n = blockIdx.x * 128 + t;
    if (n >= N) return;

    float h[HIDC];
    #pragma unroll
    for (int k = 0; k < HIDC; ++k) h[k] = s_fcb[k];
    const float* xr = x + (size_t)n * IN_F;
    for (int d = 0; d < IN_F; ++d) {
        float xv = xr[d];
        #pragma unroll
        for (int k = 0; k < HIDC; ++k) h[k] += xv * s_fc[k * IN_F + d];
    }

    float* xpr = xp + (size_t)n * HHID;
    for (int hh = 0; hh < NHEAD; ++hh) {
        float as = 0.f, ad = 0.f;
        #pragma unroll
        for (int c = 0; c < HIDC; ++c) {
            int j = hh * HIDC + c;
            float v = 0.f;
            #pragma unroll
            for (int k = 0; k < HIDC; ++k) v += h[k] * s_lin[j * HIDC + k];
            xpr[j] = v;
            as += v * s_as[j];
            ad += v * s_ad[j];
        }
        a_src[n * NHEAD + hh] = as;
        a_dst[n * NHEAD + hh] = ad;
    }
}

// ---------------------------------------------------------------------------
// In-degree count (int atomics, 40 KB target stays L2-resident).
__global__ __launch_bounds__(256) void k_deg(const int* __restrict__ ei,
                                             int* __restrict__ deg, int E) {
    int e = blockIdx.x * 256 + threadIdx.x;
    if (e < E) atomicAdd(&deg[ei[E + e]], 1);
}

// ---------------------------------------------------------------------------
// Exclusive scan, single block, chunk-per-thread + wave-shuffle (3 barriers).
// Handles N <= 16384. Writes start[0..N] and seeds cursor = start.
__global__ __launch_bounds__(1024) void k_scan(const int* __restrict__ deg,
                                               int* __restrict__ start,
                                               int* __restrict__ cursor, int N) {
    const int CH = 16;
    __shared__ int s_w[16];
    int t = threadIdx.x;
    int lane = t & 63, wid = t >> 6;
    int vals[CH];
    int base_i = t * CH;
    int s = 0;
    #pragma unroll
    for (int i = 0; i < CH; ++i) {
        int idx = base_i + i;
        int v = (idx < N) ? deg[idx] : 0;
        vals[i] = v;
        s += v;
    }
    int inc = s;
    #pragma unroll
    for (int off = 1; off < 64; off <<= 1) {
        int u = __shfl_up(inc, off, 64);
        if (lane >= off) inc += u;
    }
    if (lane == 63) s_w[wid] = inc;
    __syncthreads();
    if (wid == 0) {
        int wv = (lane < 16) ? s_w[lane] : 0;
        #pragma unroll
        for (int off = 1; off < 16; off <<= 1) {
            int u = __shfl_up(wv, off, 64);
            if (lane >= off) wv += u;
        }
        if (lane < 16) s_w[lane] = wv;
    }
    __syncthreads();
    int base = inc - s + (wid > 0 ? s_w[wid - 1] : 0);
    #pragma unroll
    for (int i = 0; i < CH; ++i) {
        int idx = base_i + i;
        if (idx < N) { start[idx] = base; cursor[idx] = base; }
        base += vals[i];
    }
    if (t == 0) start[N] = s_w[15];
}

// ---------------------------------------------------------------------------
// Per edge: compute ex = exp(LeakyReLU(a_src[s]+a_dst[d]+a_edge)) and scatter
// it (f16x8, one 16B store) plus src (4B) directly into the CSR slot.
// wcomb (att_edge folded into lin_edge_w) computed per-block in the prologue.
__global__ __launch_bounds__(256) void k_fill(const float* __restrict__ ea,
                                              const int* __restrict__ ei,
                                              const float* __restrict__ a_src,
                                              const float* __restrict__ a_dst,
                                              const float* __restrict__ att_edge,
                                              const float* __restrict__ lin_edge_w,
                                              int* __restrict__ cursor,
                                              int* __restrict__ src_csr,
                                              unsigned short* __restrict__ exh,
                                              int E) {
    __shared__ float s_w[64];
    int t = threadIdx.x;
    if (t < 64) {
        int h = t >> 3, d = t & 7;
        float s = 0.f;
        #pragma unroll
        for (int c = 0; c < HIDC; ++c)
            s += att_edge[h * HIDC + c] * lin_edge_w[(h * HIDC + c) * EDIM + d];
        s_w[t] = s;
    }
    __syncthreads();
    int e = blockIdx.x * 256 + t;
    if (e >= E) return;

    int s = ei[e];
    int d = ei[E + e];
    int pos = atomicAdd(&cursor[d], 1);

    float4 ea0 = *(const float4*)(ea + (size_t)e * EDIM);
    float4 ea1 = *(const float4*)(ea + (size_t)e * EDIM + 4);
    float eav[8] = {ea0.x, ea0.y, ea0.z, ea0.w, ea1.x, ea1.y, ea1.z, ea1.w};

    float4 as0 = *(const float4*)(a_src + (size_t)s * NHEAD);
    float4 as1 = *(const float4*)(a_src + (size_t)s * NHEAD + 4);
    float4 ad0 = *(const float4*)(a_dst + (size_t)d * NHEAD);
    float4 ad1 = *(const float4*)(a_dst + (size_t)d * NHEAD + 4);
    float asv[8] = {as0.x, as0.y, as0.z, as0.w, as1.x, as1.y, as1.z, as1.w};
    float adv[8] = {ad0.x, ad0.y, ad0.z, ad0.w, ad1.x, ad1.y, ad1.z, ad1.w};

    float exs[8];
    #pragma unroll
    for (int h = 0; h < NHEAD; ++h) {
        float aev = 0.f;
        #pragma unroll
        for (int dd = 0; dd < EDIM; ++dd) aev += eav[dd] * s_w[h * EDIM + dd];
        float lg = asv[h] + adv[h] + aev;
        lg = (lg >= 0.f) ? lg : 0.2f * lg;
        exs[h] = __expf(lg);
    }
    unsigned int pk[4];
    #pragma unroll
    for (int j = 0; j < 4; ++j) {
        unsigned short lo = __half_as_ushort(__float2half_rn(exs[2 * j]));
        unsigned short hi = __half_as_ushort(__float2half_rn(exs[2 * j + 1]));
        pk[j] = (unsigned int)lo | ((unsigned int)hi << 16);
    }
    src_csr[pos] = s;
    *(uint4*)(exh + (size_t)pos * 8) = make_uint4(pk[0], pk[1], pk[2], pk[3]);
}

// ---------------------------------------------------------------------------
// One block (128 thr) per destination node; thread t owns (h,c) = (t>>4,t&15).
// All CSR reads contiguous; only xp rows are gathered (L2/L3-resident).
__global__ __launch_bounds__(128) void k_gather(const int* __restrict__ src_csr,
                                                const int* __restrict__ start,
                                                const unsigned short* __restrict__ exh,
                                                const float* __restrict__ xp,
                                                const float* __restrict__ conv_bias,
                                                const float* __restrict__ attn_w,
                                                const float* __restrict__ attn_b,
                                                float* __restrict__ out_feat,
                                                float* __restrict__ score,
                                                float* __restrict__ attn66,
                                                int N) {
    int n = blockIdx.x;
    int t = threadIdx.x;
    int h = t >> 4;

    __shared__ int s_s[128];
    __shared__ float s_ex[128 * NHEAD];
    __shared__ float sred[128];
    __shared__ float sden[NHEAD];

    int s0 = start[n];
    int s1 = start[n + 1];

    float acc = 0.f;
    float den = 0.f;   // lanes with (t&15)==0
    float a66 = 0.f;   // lane 0 of block 6

    for (int base = s0; base < s1; base += 128) {
        int m = s1 - base; if (m > 128) m = 128;
        __syncthreads();
        if (t < m) {
            s_s[t] = src_csr[base + t];
            uint4 u = *(const uint4*)(exh + (size_t)(base + t) * 8);
            float2 f0 = __half22float2(*reinterpret_cast<const __half2*>(&u.x));
            float2 f1 = __half22float2(*reinterpret_cast<const __half2*>(&u.y));
            float2 f2 = __half22float2(*reinterpret_cast<const __half2*>(&u.z));
            float2 f3 = __half22float2(*reinterpret_cast<const __half2*>(&u.w));
            float* row = s_ex + t * NHEAD;
            row[0] = f0.x; row[1] = f0.y; row[2] = f1.x; row[3] = f1.y;
            row[4] = f2.x; row[5] = f2.y; row[6] = f3.x; row[7] = f3.y;
        }
        __syncthreads();
        for (int i = 0; i < m; ++i) {
            float ev = s_ex[i * NHEAD + h];
            acc += ev * xp[(size_t)s_s[i] * HHID + t];
            if ((t & 15) == 0) den += ev;
            if (t == 0 && n == 6 && s_s[i] == 6) a66 += ev;
        }
    }

    if ((t & 15) == 0) sden[h] = den;
    __syncthreads();
    float inv = 1.f / (sden[h] + 1e-16f);
    acc *= inv;
    if (n == 6 && t == 0) attn66[0] = a66 / (sden[0] + 1e-16f);

    sred[t] = acc;
    __syncthreads();
    if (t < HIDC) {
        float sum = 0.f;
        #pragma unroll
        for (int hh = 0; hh < NHEAD; ++hh) sum += sred[hh * HIDC + t];
        float v = sum * 0.125f + conv_bias[t];
        v = (v > 0.f) ? v : expm1f(v);
        out_feat[n * HIDC + t] = v;
        sred[t] = v * attn_w[t];
    }
    __syncthreads();
    if (t == 0) {
        float sc = 0.f;
        #pragma unroll
        for (int c = 0; c < HIDC; ++c) sc += sred[c];
        score[n] = sc + attn_b[0];
    }
}

// ---------------------------------------------------------------------------
// Single block: node-softmax stats; also seed d_out with bias + attn66.
__global__ __launch_bounds__(1024) void k_reduce(const float* __restrict__ score,
                                                 int N, float* __restrict__ red,
                                                 const float* __restrict__ out_b,
                                                 const float* __restrict__ attn66,
                                                 float* __restrict__ d_out) {
    __shared__ float sm[1024];
    int t = threadIdx.x;
    float mx = -1e30f;
    for (int i = t; i < N; i += 1024) mx = fmaxf(mx, score[i]);
    sm[t] = mx; __syncthreads();
    for (int s2 = 512; s2 > 0; s2 >>= 1) {
        if (t < s2) sm[t] = fmaxf(sm[t], sm[t + s2]);
        __syncthreads();
    }
    mx = sm[0]; __syncthreads();
    float se = 0.f;
    for (int i = t; i < N; i += 1024) se += __expf(score[i] - mx);
    sm[t] = se; __syncthreads();
    for (int s2 = 512; s2 > 0; s2 >>= 1) {
        if (t < s2) sm[t] += sm[t + s2];
        __syncthreads();
    }
    if (t == 0) { red[0] = mx; red[1] = sm[0]; }
    if (t < 3) d_out[t] = out_b[t];
    if (t == 3) d_out[3] = attn66[0];
}

// ---------------------------------------------------------------------------
// y[o] += sum_i (out_feat[i]*w[n]) * out_w[o*N*16 + i]
__global__ __launch_bounds__(256) void k_final(const float* __restrict__ out_feat,
                                               const float* __restrict__ score,
                                               const float* __restrict__ red,
                                               const float* __restrict__ out_w,
                                               float* __restrict__ d_out,
                                               int N) {
    float mx = red[0];
    float inv_se = 1.0f / red[1];
    int total = N * HIDC;
    float p0 = 0.f, p1 = 0.f, p2 = 0.f;
    for (int i = blockIdx.x * blockDim.x + threadIdx.x; i < total;
         i += gridDim.x * blockDim.x) {
        int n = i >> 4;
        float w = __expf(score[n] - mx) * inv_se;
        float f = out_feat[i] * w;
        p0 += f * out_w[i];
        p1 += f * out_w[total + i];
        p2 += f * out_w[2 * total + i];
    }
    #pragma unroll
    for (int off = 32; off > 0; off >>= 1) {
        p0 += __shfl_down(p0, off);
        p1 += __shfl_down(p1, off);
        p2 += __shfl_down(p2, off);
    }
    if ((threadIdx.x & 63) == 0) {
        atomicAdd(&d_out[0], p0);
        atomicAdd(&d_out[1], p1);
        atomicAdd(&d_out[2], p2);
    }
}

// ---------------------------------------------------------------------------
extern "C" void kernel_launch(void* const* d_in, const int* in_sizes, int n_in,
                              void* d_out, int out_size, void* d_ws, size_t ws_size,
                              hipStream_t stream) {
    const float* x          = (const float*)d_in[0];
    const float* edge_attr  = (const float*)d_in[1];
    const float* fc_w       = (const float*)d_in[2];
    const float* fc_b       = (const float*)d_in[3];
    const float* lin_w      = (const float*)d_in[4];
    const float* att_src    = (const float*)d_in[5];
    const float* att_dst    = (const float*)d_in[6];
    const float* att_edge   = (const float*)d_in[7];
    const float* lin_edge_w = (const float*)d_in[8];
    const float* conv_bias  = (const float*)d_in[9];
    const float* attn_fc_w  = (const float*)d_in[10];
    const float* attn_fc_b  = (const float*)d_in[11];
    const float* out_w      = (const float*)d_in[12];
    const float* out_b      = (const float*)d_in[13];
    const int*   edge_index = (const int*)d_in[14];
    float* out = (float*)d_out;

    const int N = in_sizes[0] / IN_F;
    const int E = in_sizes[14] / 2;

    // workspace layout (floats; exh region 16B-aligned)
    float* ws = (float*)d_ws;
    size_t off = 0;
    float* xp       = ws + off; off += (size_t)N * HHID;    // 1,280,000
    float* a_src    = ws + off; off += (size_t)N * NHEAD;   //    80,000
    float* a_dst    = ws + off; off += (size_t)N * NHEAD;   //    80,000
    float* out_feat = ws + off; off += (size_t)N * HIDC;    //   160,000
    float* score    = ws + off; off += (size_t)N;           //    10,000
    float* attn66   = ws + off; off += 1;
    float* red      = ws + off; off += 2;
    off += 1; // pad to 16B boundary
    unsigned short* exh = (unsigned short*)(ws + off); off += (size_t)E * 4; // E*8 halves
    int* iws = (int*)(ws + off);
    size_t ioff = 0;
    int* deg     = iws + ioff; ioff += N;       // ---- zeroed each call ----
    int* cursor  = iws + ioff; ioff += N;       // seeded by k_scan
    int* start   = iws + ioff; ioff += N + 1;
    int* src_csr = iws + ioff; ioff += E;

    hipMemsetAsync(deg, 0, (size_t)N * sizeof(int), stream);

    k_node<<<(N + 127) / 128, 128, 0, stream>>>(x, fc_w, fc_b, lin_w, att_src, att_dst,
                                                xp, a_src, a_dst, N);
    k_deg<<<(E + 255) / 256, 256, 0, stream>>>(edge_index, deg, E);
    k_scan<<<1, 1024, 0, stream>>>(deg, start, cursor, N);
    k_fill<<<(E + 255) / 256, 256, 0, stream>>>(edge_attr, edge_index, a_src, a_dst,
                                                att_edge, lin_edge_w, cursor,
                                                src_csr, exh, E);
    k_gather<<<N, 128, 0, stream>>>(src_csr, start, exh, xp, conv_bias,
                                    attn_fc_w, attn_fc_b, out_feat, score, attn66, N);
    k_reduce<<<1, 1024, 0, stream>>>(score, N, red, out_b, attn66, out);
    k_final<<<256, 256, 0, stream>>>(out_feat, score, red, out_w, out, N);
}

// Round 4
// 179.935 us; speedup vs baseline: 27.4689x; 1.2213x over previous
//
#include <hip/hip_runtime.h>
#include <hip/hip_fp16.h>

#define IN_F 128
#define HIDC 16
#define NHEAD 8
#define HHID 128   // NHEAD*HIDC
#define EDIM 8

// ---------------------------------------------------------------------------
// Fused: node blocks [0, NB_NODE) do the node transform; blocks >= NB_NODE
// grid-stride the edges computing deg + rank (rank = slot within dst bucket).
__global__ __launch_bounds__(128) void k_node_deg(const float* __restrict__ x,
                                                  const float* __restrict__ fc_w,
                                                  const float* __restrict__ fc_b,
                                                  const float* __restrict__ lin_w,
                                                  const float* __restrict__ att_src,
                                                  const float* __restrict__ att_dst,
                                                  const int* __restrict__ ei,
                                                  __half* __restrict__ xp_h,
                                                  float* __restrict__ a_src,
                                                  float* __restrict__ a_dst,
                                                  int* __restrict__ deg,
                                                  int* __restrict__ rank_,
                                                  int N, int E, int NB_NODE) {
    int t = threadIdx.x;
    if ((int)blockIdx.x >= NB_NODE) {
        int nb = gridDim.x - NB_NODE;
        for (int e = (blockIdx.x - NB_NODE) * 128 + t; e < E; e += nb * 128)
            rank_[e] = atomicAdd(&deg[ei[E + e]], 1);
        return;
    }

    __shared__ float s_fc[HIDC * IN_F];    // [16][128]
    __shared__ float s_lin[HHID * HIDC];   // [128][16]
    __shared__ float s_as[HHID], s_ad[HHID], s_fcb[HIDC];
    for (int i = t; i < HIDC * IN_F; i += 128) s_fc[i] = fc_w[i];
    for (int i = t; i < HHID * HIDC; i += 128) s_lin[i] = lin_w[i];
    if (t < HHID) { s_as[t] = att_src[t]; s_ad[t] = att_dst[t]; }
    if (t < HIDC) s_fcb[t] = fc_b[t];
    __syncthreads();

    int n = blockIdx.x * 128 + t;
    if (n >= N) return;

    float h[HIDC];
    #pragma unroll
    for (int k = 0; k < HIDC; ++k) h[k] = s_fcb[k];
    const float* xr = x + (size_t)n * IN_F;
    for (int d = 0; d < IN_F; ++d) {
        float xv = xr[d];
        #pragma unroll
        for (int k = 0; k < HIDC; ++k) h[k] += xv * s_fc[k * IN_F + d];
    }

    __half* xph = xp_h + (size_t)n * HHID;
    for (int hh = 0; hh < NHEAD; ++hh) {
        float as = 0.f, ad = 0.f;
        unsigned int pk[8];
        #pragma unroll
        for (int c2 = 0; c2 < 8; ++c2) {
            float v2[2];
            #pragma unroll
            for (int u = 0; u < 2; ++u) {
                int c = c2 * 2 + u;
                int j = hh * HIDC + c;
                float v = 0.f;
                #pragma unroll
                for (int k = 0; k < HIDC; ++k) v += h[k] * s_lin[j * HIDC + k];
                v2[u] = v;
                as += v * s_as[j];
                ad += v * s_ad[j];
            }
            unsigned short lo = __half_as_ushort(__float2half_rn(v2[0]));
            unsigned short hi = __half_as_ushort(__float2half_rn(v2[1]));
            pk[c2] = (unsigned int)lo | ((unsigned int)hi << 16);
        }
        // 32B contiguous store for this head's 16 halves
        *(uint4*)(xph + hh * HIDC)     = make_uint4(pk[0], pk[1], pk[2], pk[3]);
        *(uint4*)(xph + hh * HIDC + 8) = make_uint4(pk[4], pk[5], pk[6], pk[7]);
        a_src[n * NHEAD + hh] = as;
        a_dst[n * NHEAD + hh] = ad;
    }
}

// ---------------------------------------------------------------------------
// Exclusive scan, single block, chunk-per-thread + wave-shuffle (3 barriers).
__global__ __launch_bounds__(1024) void k_scan(const int* __restrict__ deg,
                                               int* __restrict__ start, int N) {
    const int CH = 16;
    __shared__ int s_w[16];
    int t = threadIdx.x;
    int lane = t & 63, wid = t >> 6;
    int vals[CH];
    int base_i = t * CH;
    int s = 0;
    #pragma unroll
    for (int i = 0; i < CH; ++i) {
        int idx = base_i + i;
        int v = (idx < N) ? deg[idx] : 0;
        vals[i] = v;
        s += v;
    }
    int inc = s;
    #pragma unroll
    for (int off = 1; off < 64; off <<= 1) {
        int u = __shfl_up(inc, off, 64);
        if (lane >= off) inc += u;
    }
    if (lane == 63) s_w[wid] = inc;
    __syncthreads();
    if (wid == 0) {
        int wv = (lane < 16) ? s_w[lane] : 0;
        #pragma unroll
        for (int off = 1; off < 16; off <<= 1) {
            int u = __shfl_up(wv, off, 64);
            if (lane >= off) wv += u;
        }
        if (lane < 16) s_w[lane] = wv;
    }
    __syncthreads();
    int base = inc - s + (wid > 0 ? s_w[wid - 1] : 0);
    #pragma unroll
    for (int i = 0; i < CH; ++i) {
        int idx = base_i + i;
        if (idx < N) start[idx] = base;
        base += vals[i];
    }
    if (t == 0) start[N] = s_w[15];
}

// ---------------------------------------------------------------------------
// Per edge: ex = exp(LeakyReLU(a_src[s]+a_dst[d]+a_edge)); write one 32B
// record {ex[8] f16, src} at CSR slot start[d]+rank[e]. No atomics.
__global__ __launch_bounds__(256) void k_fill(const float* __restrict__ ea,
                                              const int* __restrict__ ei,
                                              const float* __restrict__ a_src,
                                              const float* __restrict__ a_dst,
                                              const float* __restrict__ att_edge,
                                              const float* __restrict__ lin_edge_w,
                                              const int* __restrict__ start,
                                              const int* __restrict__ rank_,
                                              uint4* __restrict__ rec,
                                              int E) {
    __shared__ float s_w[64];
    int t = threadIdx.x;
    if (t < 64) {
        int h = t >> 3, d = t & 7;
        float s = 0.f;
        #pragma unroll
        for (int c = 0; c < HIDC; ++c)
            s += att_edge[h * HIDC + c] * lin_edge_w[(h * HIDC + c) * EDIM + d];
        s_w[t] = s;
    }
    __syncthreads();
    int e = blockIdx.x * 256 + t;
    if (e >= E) return;

    int s = ei[e];
    int d = ei[E + e];
    int pos = start[d] + rank_[e];

    float4 ea0 = *(const float4*)(ea + (size_t)e * EDIM);
    float4 ea1 = *(const float4*)(ea + (size_t)e * EDIM + 4);
    float eav[8] = {ea0.x, ea0.y, ea0.z, ea0.w, ea1.x, ea1.y, ea1.z, ea1.w};

    float4 as0 = *(const float4*)(a_src + (size_t)s * NHEAD);
    float4 as1 = *(const float4*)(a_src + (size_t)s * NHEAD + 4);
    float4 ad0 = *(const float4*)(a_dst + (size_t)d * NHEAD);
    float4 ad1 = *(const float4*)(a_dst + (size_t)d * NHEAD + 4);
    float asv[8] = {as0.x, as0.y, as0.z, as0.w, as1.x, as1.y, as1.z, as1.w};
    float adv[8] = {ad0.x, ad0.y, ad0.z, ad0.w, ad1.x, ad1.y, ad1.z, ad1.w};

    float exs[8];
    #pragma unroll
    for (int h = 0; h < NHEAD; ++h) {
        float aev = 0.f;
        #pragma unroll
        for (int dd = 0; dd < EDIM; ++dd) aev += eav[dd] * s_w[h * EDIM + dd];
        float lg = asv[h] + adv[h] + aev;
        lg = (lg >= 0.f) ? lg : 0.2f * lg;
        exs[h] = __expf(lg);
    }
    unsigned int pk[4];
    #pragma unroll
    for (int j = 0; j < 4; ++j) {
        unsigned short lo = __half_as_ushort(__float2half_rn(exs[2 * j]));
        unsigned short hi = __half_as_ushort(__float2half_rn(exs[2 * j + 1]));
        pk[j] = (unsigned int)lo | ((unsigned int)hi << 16);
    }
    rec[(size_t)pos * 2] = make_uint4(pk[0], pk[1], pk[2], pk[3]);
    ((int*)rec)[(size_t)pos * 8 + 4] = s;   // same 64B line as the uint4
}

// ---------------------------------------------------------------------------
// One block (128 thr) per destination node; thread t owns (h,c) = (t>>4,t&15).
// CSR records read contiguously; only xp_h rows gathered (L2-resident 2.6 MB).
__global__ __launch_bounds__(128) void k_gather(const uint4* __restrict__ rec,
                                                const int* __restrict__ start,
                                                const __half* __restrict__ xp_h,
                                                const float* __restrict__ conv_bias,
                                                const float* __restrict__ attn_w,
                                                const float* __restrict__ attn_b,
                                                float* __restrict__ out_feat,
                                                float* __restrict__ score,
                                                float* __restrict__ attn66,
                                                int N) {
    int n = blockIdx.x;
    int t = threadIdx.x;
    int h = t >> 4;

    __shared__ int s_s[128];
    __shared__ float s_ex[128 * NHEAD];
    __shared__ float sred[128];
    __shared__ float sden[NHEAD];

    int s0 = start[n];
    int s1 = start[n + 1];

    float acc = 0.f;
    float den = 0.f;   // lanes with (t&15)==0
    float a66 = 0.f;   // lane 0 of block 6

    for (int base = s0; base < s1; base += 128) {
        int m = s1 - base; if (m > 128) m = 128;
        __syncthreads();
        if (t < m) {
            size_t p = (size_t)(base + t);
            uint4 u = rec[p * 2];
            s_s[t] = ((const int*)rec)[p * 8 + 4];
            float2 f0 = __half22float2(*reinterpret_cast<const __half2*>(&u.x));
            float2 f1 = __half22float2(*reinterpret_cast<const __half2*>(&u.y));
            float2 f2 = __half22float2(*reinterpret_cast<const __half2*>(&u.z));
            float2 f3 = __half22float2(*reinterpret_cast<const __half2*>(&u.w));
            float* row = s_ex + t * NHEAD;
            row[0] = f0.x; row[1] = f0.y; row[2] = f1.x; row[3] = f1.y;
            row[4] = f2.x; row[5] = f2.y; row[6] = f3.x; row[7] = f3.y;
        }
        __syncthreads();
        for (int i = 0; i < m; ++i) {
            float ev = s_ex[i * NHEAD + h];
            acc += ev * __half2float(xp_h[(size_t)s_s[i] * HHID + t]);
            if ((t & 15) == 0) den += ev;
            if (t == 0 && n == 6 && s_s[i] == 6) a66 += ev;
        }
    }

    if ((t & 15) == 0) sden[h] = den;
    __syncthreads();
    float inv = 1.f / (sden[h] + 1e-16f);
    acc *= inv;
    if (n == 6 && t == 0) attn66[0] = a66 / (sden[0] + 1e-16f);

    sred[t] = acc;
    __syncthreads();
    if (t < HIDC) {
        float sum = 0.f;
        #pragma unroll
        for (int hh = 0; hh < NHEAD; ++hh) sum += sred[hh * HIDC + t];
        float v = sum * 0.125f + conv_bias[t];
        v = (v > 0.f) ? v : expm1f(v);
        out_feat[n * HIDC + t] = v;
        sred[t] = v * attn_w[t];
    }
    __syncthreads();
    if (t == 0) {
        float sc = 0.f;
        #pragma unroll
        for (int c = 0; c < HIDC; ++c) sc += sred[c];
        score[n] = sc + attn_b[0];
    }
}

// ---------------------------------------------------------------------------
// Single block: node-softmax stats; also seed d_out with bias + attn66.
__global__ __launch_bounds__(1024) void k_reduce(const float* __restrict__ score,
                                                 int N, float* __restrict__ red,
                                                 const float* __restrict__ out_b,
                                                 const float* __restrict__ attn66,
                                                 float* __restrict__ d_out) {
    __shared__ float sm[1024];
    int t = threadIdx.x;
    float mx = -1e30f;
    for (int i = t; i < N; i += 1024) mx = fmaxf(mx, score[i]);
    sm[t] = mx; __syncthreads();
    for (int s2 = 512; s2 > 0; s2 >>= 1) {
        if (t < s2) sm[t] = fmaxf(sm[t], sm[t + s2]);
        __syncthreads();
    }
    mx = sm[0]; __syncthreads();
    float se = 0.f;
    for (int i = t; i < N; i += 1024) se += __expf(score[i] - mx);
    sm[t] = se; __syncthreads();
    for (int s2 = 512; s2 > 0; s2 >>= 1) {
        if (t < s2) sm[t] += sm[t + s2];
        __syncthreads();
    }
    if (t == 0) { red[0] = mx; red[1] = sm[0]; }
    if (t < 3) d_out[t] = out_b[t];
    if (t == 3) d_out[3] = attn66[0];
}

// ---------------------------------------------------------------------------
// y[o] += sum_i (out_feat[i]*w[n]) * out_w[o*N*16 + i]
__global__ __launch_bounds__(256) void k_final(const float* __restrict__ out_feat,
                                               const float* __restrict__ score,
                                               const float* __restrict__ red,
                                               const float* __restrict__ out_w,
                                               float* __restrict__ d_out,
                                               int N) {
    float mx = red[0];
    float inv_se = 1.0f / red[1];
    int total = N * HIDC;
    float p0 = 0.f, p1 = 0.f, p2 = 0.f;
    for (int i = blockIdx.x * blockDim.x + threadIdx.x; i < total;
         i += gridDim.x * blockDim.x) {
        int n = i >> 4;
        float w = __expf(score[n] - mx) * inv_se;
        float f = out_feat[i] * w;
        p0 += f * out_w[i];
        p1 += f * out_w[total + i];
        p2 += f * out_w[2 * total + i];
    }
    #pragma unroll
    for (int off = 32; off > 0; off >>= 1) {
        p0 += __shfl_down(p0, off);
        p1 += __shfl_down(p1, off);
        p2 += __shfl_down(p2, off);
    }
    if ((threadIdx.x & 63) == 0) {
        atomicAdd(&d_out[0], p0);
        atomicAdd(&d_out[1], p1);
        atomicAdd(&d_out[2], p2);
    }
}

// ---------------------------------------------------------------------------
extern "C" void kernel_launch(void* const* d_in, const int* in_sizes, int n_in,
                              void* d_out, int out_size, void* d_ws, size_t ws_size,
                              hipStream_t stream) {
    const float* x          = (const float*)d_in[0];
    const float* edge_attr  = (const float*)d_in[1];
    const float* fc_w       = (const float*)d_in[2];
    const float* fc_b       = (const float*)d_in[3];
    const float* lin_w      = (const float*)d_in[4];
    const float* att_src    = (const float*)d_in[5];
    const float* att_dst    = (const float*)d_in[6];
    const float* att_edge   = (const float*)d_in[7];
    const float* lin_edge_w = (const float*)d_in[8];
    const float* conv_bias  = (const float*)d_in[9];
    const float* attn_fc_w  = (const float*)d_in[10];
    const float* attn_fc_b  = (const float*)d_in[11];
    const float* out_w      = (const float*)d_in[12];
    const float* out_b      = (const float*)d_in[13];
    const int*   edge_index = (const int*)d_in[14];
    float* out = (float*)d_out;

    const int N = in_sizes[0] / IN_F;
    const int E = in_sizes[14] / 2;

    // workspace layout (descending alignment)
    char* w = (char*)d_ws;
    uint4* rec      = (uint4*)w;           w += (size_t)E * 32;          // 20.5 MB
    __half* xp_h    = (__half*)w;          w += (size_t)N * HHID * 2;    //  2.6 MB
    float* a_src    = (float*)w;           w += (size_t)N * NHEAD * 4;
    float* a_dst    = (float*)w;           w += (size_t)N * NHEAD * 4;
    float* out_feat = (float*)w;           w += (size_t)N * HIDC * 4;
    float* score    = (float*)w;           w += (size_t)N * 4;
    float* attn66   = (float*)w;           w += 4;
    float* red      = (float*)w;           w += 8;
    int* deg        = (int*)w;             w += (size_t)N * 4;   // zeroed each call
    int* start      = (int*)w;             w += (size_t)(N + 1) * 4;
    int* rank_      = (int*)w;             w += (size_t)E * 4;

    hipMemsetAsync(deg, 0, (size_t)N * sizeof(int), stream);

    const int NB_NODE = (N + 127) / 128;
    const int DEG_BLOCKS = 1024;
    k_node_deg<<<NB_NODE + DEG_BLOCKS, 128, 0, stream>>>(
        x, fc_w, fc_b, lin_w, att_src, att_dst, edge_index,
        xp_h, a_src, a_dst, deg, rank_, N, E, NB_NODE);
    k_scan<<<1, 1024, 0, stream>>>(deg, start, N);
    k_fill<<<(E + 255) / 256, 256, 0, stream>>>(edge_attr, edge_index, a_src, a_dst,
                                                att_edge, lin_edge_w, start, rank_,
                                                rec, E);
    k_gather<<<N, 128, 0, stream>>>(rec, start, xp_h, conv_bias,
                                    attn_fc_w, attn_fc_b, out_feat, score, attn66, N);
    k_reduce<<<1, 1024, 0, stream>>>(score, N, red, out_b, attn66, out);
    k_final<<<256, 256, 0, stream>>>(out_feat, score, red, out_w, out, N);
}

// Round 5
// 154.222 us; speedup vs baseline: 32.0487x; 1.1667x over previous
//
#include <hip/hip_runtime.h>
#include <hip/hip_fp16.h>

#define IN_F 128
#define HIDC 16
#define NHEAD 8
#define HHID 128   // NHEAD*HIDC
#define EDIM 8
#define MAXN 10240 // LDS histogram capacity (N=10000)
#define HB   128   // histogram blocks (counting-sort partitions)

// ---------------------------------------------------------------------------
// Node transform: 32 nodes per 256-thread block, x staged in LDS.
// Stage2: (k,n) threads compute h = x@fc_w.T + fc_b.
// Stage3: (head,n) threads compute xp row (f16) + a_src/a_dst dots.
__global__ __launch_bounds__(256) void k_node(const float* __restrict__ x,
                                              const float* __restrict__ fc_w,
                                              const float* __restrict__ fc_b,
                                              const float* __restrict__ lin_w,
                                              const float* __restrict__ att_src,
                                              const float* __restrict__ att_dst,
                                              __half* __restrict__ xp_h,
                                              float* __restrict__ a_src,
                                              float* __restrict__ a_dst,
                                              int N) {
    __shared__ float s_x[32 * 129];     // pad 129: conflict-free
    __shared__ float s_fc[16 * 129];
    __shared__ float s_lin[128 * 17];
    __shared__ float s_h[32 * 17];
    __shared__ float s_as[HHID], s_ad[HHID], s_fcb[HIDC];

    int t = threadIdx.x;
    int n0 = blockIdx.x * 32;

    // stage weights
    for (int i = t; i < HIDC * IN_F; i += 256) s_fc[(i >> 7) * 129 + (i & 127)] = fc_w[i];
    for (int i = t; i < HHID * HIDC; i += 256) s_lin[(i >> 4) * 17 + (i & 15)] = lin_w[i];
    if (t < HHID) { s_as[t] = att_src[t]; s_ad[t] = att_dst[t]; }
    if (t < HIDC) s_fcb[t] = fc_b[t];
    // stage x tile (coalesced)
    for (int i = t; i < 32 * IN_F; i += 256) {
        size_t g = (size_t)n0 * IN_F + i;
        s_x[(i >> 7) * 129 + (i & 127)] = (g < (size_t)N * IN_F) ? x[g] : 0.f;
    }
    __syncthreads();

    // stage 2: h[n][k], thread handles (k, k+8) for one n
    {
        int k = t >> 5, n_l = t & 31;
        float a0 = 0.f, a1 = 0.f;
        #pragma unroll 8
        for (int d = 0; d < IN_F; ++d) {
            float xv = s_x[n_l * 129 + d];
            a0 += xv * s_fc[k * 129 + d];
            a1 += xv * s_fc[(k + 8) * 129 + d];
        }
        s_h[n_l * 17 + k]     = a0 + s_fcb[k];
        s_h[n_l * 17 + k + 8] = a1 + s_fcb[k + 8];
    }
    __syncthreads();

    // stage 3: thread handles (head, n_l): 16 xp values + as/ad
    int head = t >> 5, n_l = t & 31;
    int n = n0 + n_l;
    if (n >= N) return;

    float hreg[HIDC];
    #pragma unroll
    for (int k = 0; k < HIDC; ++k) hreg[k] = s_h[n_l * 17 + k];

    float as = 0.f, ad = 0.f;
    unsigned int pk[8];
    #pragma unroll
    for (int c2 = 0; c2 < 8; ++c2) {
        float v2[2];
        #pragma unroll
        for (int u = 0; u < 2; ++u) {
            int c = c2 * 2 + u;
            int j = head * HIDC + c;
            float v = 0.f;
            #pragma unroll
            for (int k = 0; k < HIDC; ++k) v += hreg[k] * s_lin[j * 17 + k];
            v2[u] = v;
            as += v * s_as[j];
            ad += v * s_ad[j];
        }
        unsigned short lo = __half_as_ushort(__float2half_rn(v2[0]));
        unsigned short hi = __half_as_ushort(__float2half_rn(v2[1]));
        pk[c2] = (unsigned int)lo | ((unsigned int)hi << 16);
    }
    __half* xph = xp_h + (size_t)n * HHID + head * HIDC;
    *(uint4*)(xph)     = make_uint4(pk[0], pk[1], pk[2], pk[3]);
    *(uint4*)(xph + 8) = make_uint4(pk[4], pk[5], pk[6], pk[7]);
    a_src[n * NHEAD + head] = as;
    a_dst[n * NHEAD + head] = ad;
}

// ---------------------------------------------------------------------------
// Counting sort, phase 1: per-block LDS histogram over dst + local rank.
// Block b owns edges [b*CHUNK, min((b+1)*CHUNK, E)).
__global__ __launch_bounds__(256) void k_hist(const int* __restrict__ ei,
                                              int* __restrict__ part_hist,
                                              int* __restrict__ lrank,
                                              int N, int E, int CHUNK) {
    __shared__ int lh[MAXN];
    int t = threadIdx.x;
    int b = blockIdx.x;
    for (int i = t; i < MAXN; i += 256) lh[i] = 0;
    __syncthreads();
    int e0 = b * CHUNK;
    int e1 = min(e0 + CHUNK, E);
    for (int e = e0 + t; e < e1; e += 256)
        lrank[e] = atomicAdd(&lh[ei[E + e]], 1);
    __syncthreads();
    for (int nn = t; nn < N; nn += 256) part_hist[(size_t)b * N + nn] = lh[nn];
}

// ---------------------------------------------------------------------------
// Column sums of part_hist -> deg[n]. Coalesced per-b iteration.
__global__ __launch_bounds__(256) void k_colsum(const int* __restrict__ part_hist,
                                                int* __restrict__ deg, int N) {
    int n = blockIdx.x * 256 + threadIdx.x;
    if (n >= N) return;
    int s = 0;
    for (int b = 0; b < HB; ++b) s += part_hist[(size_t)b * N + n];
    deg[n] = s;
}

// ---------------------------------------------------------------------------
// Exclusive scan, single block, chunk-per-thread + wave-shuffle (3 barriers).
__global__ __launch_bounds__(1024) void k_scan(const int* __restrict__ deg,
                                               int* __restrict__ start, int N) {
    const int CH = 16;
    __shared__ int s_w[16];
    int t = threadIdx.x;
    int lane = t & 63, wid = t >> 6;
    int vals[CH];
    int base_i = t * CH;
    int s = 0;
    #pragma unroll
    for (int i = 0; i < CH; ++i) {
        int idx = base_i + i;
        int v = (idx < N) ? deg[idx] : 0;
        vals[i] = v;
        s += v;
    }
    int inc = s;
    #pragma unroll
    for (int off = 1; off < 64; off <<= 1) {
        int u = __shfl_up(inc, off, 64);
        if (lane >= off) inc += u;
    }
    if (lane == 63) s_w[wid] = inc;
    __syncthreads();
    if (wid == 0) {
        int wv = (lane < 16) ? s_w[lane] : 0;
        #pragma unroll
        for (int off = 1; off < 16; off <<= 1) {
            int u = __shfl_up(wv, off, 64);
            if (lane >= off) wv += u;
        }
        if (lane < 16) s_w[lane] = wv;
    }
    __syncthreads();
    int base = inc - s + (wid > 0 ? s_w[wid - 1] : 0);
    #pragma unroll
    for (int i = 0; i < CH; ++i) {
        int idx = base_i + i;
        if (idx < N) start[idx] = base;
        base += vals[i];
    }
    if (t == 0) start[N] = s_w[15];
}

// ---------------------------------------------------------------------------
// Column exclusive offsets in place: part_hist[b][n] = start[n] + sum_{b'<b}.
__global__ __launch_bounds__(256) void k_coloff(int* __restrict__ part_hist,
                                                const int* __restrict__ start,
                                                int N) {
    int n = blockIdx.x * 256 + threadIdx.x;
    if (n >= N) return;
    int run = start[n];
    for (int b = 0; b < HB; ++b) {
        size_t idx = (size_t)b * N + n;
        int v = part_hist[idx];
        part_hist[idx] = run;
        run += v;
    }
}

// ---------------------------------------------------------------------------
// Per edge: ex = exp(LeakyReLU(a_src[s]+a_dst[d]+a_edge)); one 32B record
// {ex[8] f16, src} at CSR slot part_hist[b][d] + lrank[e]. No atomics.
__global__ __launch_bounds__(256) void k_fill(const float* __restrict__ ea,
                                              const int* __restrict__ ei,
                                              const float* __restrict__ a_src,
                                              const float* __restrict__ a_dst,
                                              const float* __restrict__ att_edge,
                                              const float* __restrict__ lin_edge_w,
                                              const int* __restrict__ part_hist,
                                              const int* __restrict__ lrank,
                                              uint4* __restrict__ rec,
                                              int N, int E, int CHUNK) {
    __shared__ float s_w[64];
    int t = threadIdx.x;
    if (t < 64) {
        int h = t >> 3, d = t & 7;
        float s = 0.f;
        #pragma unroll
        for (int c = 0; c < HIDC; ++c)
            s += att_edge[h * HIDC + c] * lin_edge_w[(h * HIDC + c) * EDIM + d];
        s_w[t] = s;
    }
    __syncthreads();
    int e = blockIdx.x * 256 + t;
    if (e >= E) return;

    int s = ei[e];
    int d = ei[E + e];
    int pos = part_hist[(size_t)(e / CHUNK) * N + d] + lrank[e];

    float4 ea0 = *(const float4*)(ea + (size_t)e * EDIM);
    float4 ea1 = *(const float4*)(ea + (size_t)e * EDIM + 4);
    float eav[8] = {ea0.x, ea0.y, ea0.z, ea0.w, ea1.x, ea1.y, ea1.z, ea1.w};

    float4 as0 = *(const float4*)(a_src + (size_t)s * NHEAD);
    float4 as1 = *(const float4*)(a_src + (size_t)s * NHEAD + 4);
    float4 ad0 = *(const float4*)(a_dst + (size_t)d * NHEAD);
    float4 ad1 = *(const float4*)(a_dst + (size_t)d * NHEAD + 4);
    float asv[8] = {as0.x, as0.y, as0.z, as0.w, as1.x, as1.y, as1.z, as1.w};
    float adv[8] = {ad0.x, ad0.y, ad0.z, ad0.w, ad1.x, ad1.y, ad1.z, ad1.w};

    float exs[8];
    #pragma unroll
    for (int h = 0; h < NHEAD; ++h) {
        float aev = 0.f;
        #pragma unroll
        for (int dd = 0; dd < EDIM; ++dd) aev += eav[dd] * s_w[h * EDIM + dd];
        float lg = asv[h] + adv[h] + aev;
        lg = (lg >= 0.f) ? lg : 0.2f * lg;
        exs[h] = __expf(lg);
    }
    unsigned int pk[4];
    #pragma unroll
    for (int j = 0; j < 4; ++j) {
        unsigned short lo = __half_as_ushort(__float2half_rn(exs[2 * j]));
        unsigned short hi = __half_as_ushort(__float2half_rn(exs[2 * j + 1]));
        pk[j] = (unsigned int)lo | ((unsigned int)hi << 16);
    }
    rec[(size_t)pos * 2] = make_uint4(pk[0], pk[1], pk[2], pk[3]);
    ((int*)rec)[(size_t)pos * 8 + 4] = s;   // same 64B line as the uint4
}

// ---------------------------------------------------------------------------
// One block (128 thr) per destination node; thread t owns (h,c) = (t>>4,t&15).
// CSR records read contiguously; only xp_h rows gathered (L2-resident 2.6 MB).
__global__ __launch_bounds__(128) void k_gather(const uint4* __restrict__ rec,
                                                const int* __restrict__ start,
                                                const __half* __restrict__ xp_h,
                                                const float* __restrict__ conv_bias,
                                                const float* __restrict__ attn_w,
                                                const float* __restrict__ attn_b,
                                                float* __restrict__ out_feat,
                                                float* __restrict__ score,
                                                float* __restrict__ attn66,
                                                int N) {
    int n = blockIdx.x;
    int t = threadIdx.x;
    int h = t >> 4;

    __shared__ int s_s[128];
    __shared__ float s_ex[128 * NHEAD];
    __shared__ float sred[128];
    __shared__ float sden[NHEAD];

    int s0 = start[n];
    int s1 = start[n + 1];

    float acc = 0.f;
    float den = 0.f;   // lanes with (t&15)==0
    float a66 = 0.f;   // lane 0 of block 6

    for (int base = s0; base < s1; base += 128) {
        int m = s1 - base; if (m > 128) m = 128;
        __syncthreads();
        if (t < m) {
            size_t p = (size_t)(base + t);
            uint4 u = rec[p * 2];
            s_s[t] = ((const int*)rec)[p * 8 + 4];
            float2 f0 = __half22float2(*reinterpret_cast<const __half2*>(&u.x));
            float2 f1 = __half22float2(*reinterpret_cast<const __half2*>(&u.y));
            float2 f2 = __half22float2(*reinterpret_cast<const __half2*>(&u.z));
            float2 f3 = __half22float2(*reinterpret_cast<const __half2*>(&u.w));
            float* row = s_ex + t * NHEAD;
            row[0] = f0.x; row[1] = f0.y; row[2] = f1.x; row[3] = f1.y;
            row[4] = f2.x; row[5] = f2.y; row[6] = f3.x; row[7] = f3.y;
        }
        __syncthreads();
        for (int i = 0; i < m; ++i) {
            float ev = s_ex[i * NHEAD + h];
            acc += ev * __half2float(xp_h[(size_t)s_s[i] * HHID + t]);
            if ((t & 15) == 0) den += ev;
            if (t == 0 && n == 6 && s_s[i] == 6) a66 += ev;
        }
    }

    if ((t & 15) == 0) sden[h] = den;
    __syncthreads();
    float inv = 1.f / (sden[h] + 1e-16f);
    acc *= inv;
    if (n == 6 && t == 0) attn66[0] = a66 / (sden[0] + 1e-16f);

    sred[t] = acc;
    __syncthreads();
    if (t < HIDC) {
        float sum = 0.f;
        #pragma unroll
        for (int hh = 0; hh < NHEAD; ++hh) sum += sred[hh * HIDC + t];
        float v = sum * 0.125f + conv_bias[t];
        v = (v > 0.f) ? v : expm1f(v);
        out_feat[n * HIDC + t] = v;
        sred[t] = v * attn_w[t];
    }
    __syncthreads();
    if (t == 0) {
        float sc = 0.f;
        #pragma unroll
        for (int c = 0; c < HIDC; ++c) sc += sred[c];
        score[n] = sc + attn_b[0];
    }
}

// ---------------------------------------------------------------------------
// Single block: node-softmax stats; also seed d_out with bias + attn66.
__global__ __launch_bounds__(1024) void k_reduce(const float* __restrict__ score,
                                                 int N, float* __restrict__ red,
                                                 const float* __restrict__ out_b,
                                                 const float* __restrict__ attn66,
                                                 float* __restrict__ d_out) {
    __shared__ float sm[1024];
    int t = threadIdx.x;
    float mx = -1e30f;
    for (int i = t; i < N; i += 1024) mx = fmaxf(mx, score[i]);
    sm[t] = mx; __syncthreads();
    for (int s2 = 512; s2 > 0; s2 >>= 1) {
        if (t < s2) sm[t] = fmaxf(sm[t], sm[t + s2]);
        __syncthreads();
    }
    mx = sm[0]; __syncthreads();
    float se = 0.f;
    for (int i = t; i < N; i += 1024) se += __expf(score[i] - mx);
    sm[t] = se; __syncthreads();
    for (int s2 = 512; s2 > 0; s2 >>= 1) {
        if (t < s2) sm[t] += sm[t + s2];
        __syncthreads();
    }
    if (t == 0) { red[0] = mx; red[1] = sm[0]; }
    if (t < 3) d_out[t] = out_b[t];
    if (t == 3) d_out[3] = attn66[0];
}

// ---------------------------------------------------------------------------
// y[o] += sum_i (out_feat[i]*w[n]) * out_w[o*N*16 + i]
__global__ __launch_bounds__(256) void k_final(const float* __restrict__ out_feat,
                                               const float* __restrict__ score,
                                               const float* __restrict__ red,
                                               const float* __restrict__ out_w,
                                               float* __restrict__ d_out,
                                               int N) {
    float mx = red[0];
    float inv_se = 1.0f / red[1];
    int total = N * HIDC;
    float p0 = 0.f, p1 = 0.f, p2 = 0.f;
    for (int i = blockIdx.x * blockDim.x + threadIdx.x; i < total;
         i += gridDim.x * blockDim.x) {
        int n = i >> 4;
        float w = __expf(score[n] - mx) * inv_se;
        float f = out_feat[i] * w;
        p0 += f * out_w[i];
        p1 += f * out_w[total + i];
        p2 += f * out_w[2 * total + i];
    }
    #pragma unroll
    for (int off = 32; off > 0; off >>= 1) {
        p0 += __shfl_down(p0, off);
        p1 += __shfl_down(p1, off);
        p2 += __shfl_down(p2, off);
    }
    if ((threadIdx.x & 63) == 0) {
        atomicAdd(&d_out[0], p0);
        atomicAdd(&d_out[1], p1);
        atomicAdd(&d_out[2], p2);
    }
}

// ---------------------------------------------------------------------------
extern "C" void kernel_launch(void* const* d_in, const int* in_sizes, int n_in,
                              void* d_out, int out_size, void* d_ws, size_t ws_size,
                              hipStream_t stream) {
    const float* x          = (const float*)d_in[0];
    const float* edge_attr  = (const float*)d_in[1];
    const float* fc_w       = (const float*)d_in[2];
    const float* fc_b       = (const float*)d_in[3];
    const float* lin_w      = (const float*)d_in[4];
    const float* att_src    = (const float*)d_in[5];
    const float* att_dst    = (const float*)d_in[6];
    const float* att_edge   = (const float*)d_in[7];
    const float* lin_edge_w = (const float*)d_in[8];
    const float* conv_bias  = (const float*)d_in[9];
    const float* attn_fc_w  = (const float*)d_in[10];
    const float* attn_fc_b  = (const float*)d_in[11];
    const float* out_w      = (const float*)d_in[12];
    const float* out_b      = (const float*)d_in[13];
    const int*   edge_index = (const int*)d_in[14];
    float* out = (float*)d_out;

    const int N = in_sizes[0] / IN_F;
    const int E = in_sizes[14] / 2;
    const int CHUNK = (E + HB - 1) / HB;

    // workspace layout (descending alignment)
    char* w = (char*)d_ws;
    uint4* rec      = (uint4*)w;     w += (size_t)E * 32;          // 20.5 MB
    __half* xp_h    = (__half*)w;    w += (size_t)N * HHID * 2;    //  2.6 MB
    int* part_hist  = (int*)w;       w += (size_t)HB * N * 4;      //  5.1 MB
    int* lrank      = (int*)w;       w += (size_t)E * 4;           //  2.6 MB
    float* a_src    = (float*)w;     w += (size_t)N * NHEAD * 4;
    float* a_dst    = (float*)w;     w += (size_t)N * NHEAD * 4;
    float* out_feat = (float*)w;     w += (size_t)N * HIDC * 4;
    float* score    = (float*)w;     w += (size_t)N * 4;
    float* attn66   = (float*)w;     w += 4;
    float* red      = (float*)w;     w += 8;
    int* deg        = (int*)w;       w += (size_t)N * 4;
    int* start      = (int*)w;       w += (size_t)(N + 1) * 4;

    k_node<<<(N + 31) / 32, 256, 0, stream>>>(x, fc_w, fc_b, lin_w, att_src, att_dst,
                                              xp_h, a_src, a_dst, N);
    k_hist<<<HB, 256, 0, stream>>>(edge_index, part_hist, lrank, N, E, CHUNK);
    k_colsum<<<(N + 255) / 256, 256, 0, stream>>>(part_hist, deg, N);
    k_scan<<<1, 1024, 0, stream>>>(deg, start, N);
    k_coloff<<<(N + 255) / 256, 256, 0, stream>>>(part_hist, start, N);
    k_fill<<<(E + 255) / 256, 256, 0, stream>>>(edge_attr, edge_index, a_src, a_dst,
                                                att_edge, lin_edge_w, part_hist, lrank,
                                                rec, N, E, CHUNK);
    k_gather<<<N, 128, 0, stream>>>(rec, start, xp_h, conv_bias,
                                    attn_fc_w, attn_fc_b, out_feat, score, attn66, N);
    k_reduce<<<1, 1024, 0, stream>>>(score, N, red, out_b, attn66, out);
    k_final<<<256, 256, 0, stream>>>(out_feat, score, red, out_w, out, N);
}

// Round 6
// 114.595 us; speedup vs baseline: 43.1313x; 1.3458x over previous
//
#include <hip/hip_runtime.h>
#include <hip/hip_fp16.h>

#define IN_F 128
#define HIDC 16
#define NHEAD 8
#define HHID 128   // NHEAD*HIDC
#define EDIM 8
#define MAXN 10240 // LDS histogram capacity (N=10000)
#define HB   128   // histogram blocks (counting-sort partitions)
#define FB   128   // final-reduction partial blocks

// ---------------------------------------------------------------------------
// Node transform: 32 nodes per 256-thread block, x staged in LDS.
__global__ __launch_bounds__(256) void k_node(const float* __restrict__ x,
                                              const float* __restrict__ fc_w,
                                              const float* __restrict__ fc_b,
                                              const float* __restrict__ lin_w,
                                              const float* __restrict__ att_src,
                                              const float* __restrict__ att_dst,
                                              __half* __restrict__ xp_h,
                                              float* __restrict__ a_src,
                                              float* __restrict__ a_dst,
                                              int N) {
    __shared__ float s_x[32 * 129];     // pad 129: conflict-free
    __shared__ float s_fc[16 * 129];
    __shared__ float s_lin[128 * 17];
    __shared__ float s_h[32 * 17];
    __shared__ float s_as[HHID], s_ad[HHID], s_fcb[HIDC];

    int t = threadIdx.x;
    int n0 = blockIdx.x * 32;

    for (int i = t; i < HIDC * IN_F; i += 256) s_fc[(i >> 7) * 129 + (i & 127)] = fc_w[i];
    for (int i = t; i < HHID * HIDC; i += 256) s_lin[(i >> 4) * 17 + (i & 15)] = lin_w[i];
    if (t < HHID) { s_as[t] = att_src[t]; s_ad[t] = att_dst[t]; }
    if (t < HIDC) s_fcb[t] = fc_b[t];
    for (int i = t; i < 32 * IN_F; i += 256) {
        size_t g = (size_t)n0 * IN_F + i;
        s_x[(i >> 7) * 129 + (i & 127)] = (g < (size_t)N * IN_F) ? x[g] : 0.f;
    }
    __syncthreads();

    // stage 2: h[n][k], thread handles (k, k+8) for one n
    {
        int k = t >> 5, n_l = t & 31;
        float a0 = 0.f, a1 = 0.f;
        #pragma unroll 8
        for (int d = 0; d < IN_F; ++d) {
            float xv = s_x[n_l * 129 + d];
            a0 += xv * s_fc[k * 129 + d];
            a1 += xv * s_fc[(k + 8) * 129 + d];
        }
        s_h[n_l * 17 + k]     = a0 + s_fcb[k];
        s_h[n_l * 17 + k + 8] = a1 + s_fcb[k + 8];
    }
    __syncthreads();

    // stage 3: thread handles (head, n_l): 16 xp values + as/ad
    int head = t >> 5, n_l = t & 31;
    int n = n0 + n_l;
    if (n >= N) return;

    float hreg[HIDC];
    #pragma unroll
    for (int k = 0; k < HIDC; ++k) hreg[k] = s_h[n_l * 17 + k];

    float as = 0.f, ad = 0.f;
    unsigned int pk[8];
    #pragma unroll
    for (int c2 = 0; c2 < 8; ++c2) {
        float v2[2];
        #pragma unroll
        for (int u = 0; u < 2; ++u) {
            int c = c2 * 2 + u;
            int j = head * HIDC + c;
            float v = 0.f;
            #pragma unroll
            for (int k = 0; k < HIDC; ++k) v += hreg[k] * s_lin[j * 17 + k];
            v2[u] = v;
            as += v * s_as[j];
            ad += v * s_ad[j];
        }
        unsigned short lo = __half_as_ushort(__float2half_rn(v2[0]));
        unsigned short hi = __half_as_ushort(__float2half_rn(v2[1]));
        pk[c2] = (unsigned int)lo | ((unsigned int)hi << 16);
    }
    __half* xph = xp_h + (size_t)n * HHID + head * HIDC;
    *(uint4*)(xph)     = make_uint4(pk[0], pk[1], pk[2], pk[3]);
    *(uint4*)(xph + 8) = make_uint4(pk[4], pk[5], pk[6], pk[7]);
    a_src[n * NHEAD + head] = as;
    a_dst[n * NHEAD + head] = ad;
}

// ---------------------------------------------------------------------------
// Counting sort, phase 1: per-block LDS histogram over dst + local rank.
__global__ __launch_bounds__(256) void k_hist(const int* __restrict__ ei,
                                              int* __restrict__ part_hist,
                                              int* __restrict__ lrank,
                                              int N, int E, int CHUNK) {
    __shared__ int lh[MAXN];
    int t = threadIdx.x;
    int b = blockIdx.x;
    for (int i = t; i < MAXN; i += 256) lh[i] = 0;
    __syncthreads();
    int e0 = b * CHUNK;
    int e1 = min(e0 + CHUNK, E);
    for (int e = e0 + t; e < e1; e += 256)
        lrank[e] = atomicAdd(&lh[ei[E + e]], 1);
    __syncthreads();
    for (int nn = t; nn < N; nn += 256) part_hist[(size_t)b * N + nn] = lh[nn];
}

// ---------------------------------------------------------------------------
__global__ __launch_bounds__(256) void k_colsum(const int* __restrict__ part_hist,
                                                int* __restrict__ deg, int N) {
    int n = blockIdx.x * 256 + threadIdx.x;
    if (n >= N) return;
    int s = 0;
    for (int b = 0; b < HB; ++b) s += part_hist[(size_t)b * N + n];
    deg[n] = s;
}

// ---------------------------------------------------------------------------
// Exclusive scan, single block, chunk-per-thread + wave-shuffle (3 barriers).
__global__ __launch_bounds__(1024) void k_scan(const int* __restrict__ deg,
                                               int* __restrict__ start, int N) {
    const int CH = 16;
    __shared__ int s_w[16];
    int t = threadIdx.x;
    int lane = t & 63, wid = t >> 6;
    int vals[CH];
    int base_i = t * CH;
    int s = 0;
    #pragma unroll
    for (int i = 0; i < CH; ++i) {
        int idx = base_i + i;
        int v = (idx < N) ? deg[idx] : 0;
        vals[i] = v;
        s += v;
    }
    int inc = s;
    #pragma unroll
    for (int off = 1; off < 64; off <<= 1) {
        int u = __shfl_up(inc, off, 64);
        if (lane >= off) inc += u;
    }
    if (lane == 63) s_w[wid] = inc;
    __syncthreads();
    if (wid == 0) {
        int wv = (lane < 16) ? s_w[lane] : 0;
        #pragma unroll
        for (int off = 1; off < 16; off <<= 1) {
            int u = __shfl_up(wv, off, 64);
            if (lane >= off) wv += u;
        }
        if (lane < 16) s_w[lane] = wv;
    }
    __syncthreads();
    int base = inc - s + (wid > 0 ? s_w[wid - 1] : 0);
    #pragma unroll
    for (int i = 0; i < CH; ++i) {
        int idx = base_i + i;
        if (idx < N) start[idx] = base;
        base += vals[i];
    }
    if (t == 0) start[N] = s_w[15];
}

// ---------------------------------------------------------------------------
__global__ __launch_bounds__(256) void k_coloff(int* __restrict__ part_hist,
                                                const int* __restrict__ start,
                                                int N) {
    int n = blockIdx.x * 256 + threadIdx.x;
    if (n >= N) return;
    int run = start[n];
    for (int b = 0; b < HB; ++b) {
        size_t idx = (size_t)b * N + n;
        int v = part_hist[idx];
        part_hist[idx] = run;
        run += v;
    }
}

// ---------------------------------------------------------------------------
// Per edge: ex = exp(LeakyReLU(a_src[s]+a_dst[d]+a_edge)); one 32B record
// {ex[8] f16, src} at CSR slot part_hist[b][d] + lrank[e]. No atomics.
__global__ __launch_bounds__(256) void k_fill(const float* __restrict__ ea,
                                              const int* __restrict__ ei,
                                              const float* __restrict__ a_src,
                                              const float* __restrict__ a_dst,
                                              const float* __restrict__ att_edge,
                                              const float* __restrict__ lin_edge_w,
                                              const int* __restrict__ part_hist,
                                              const int* __restrict__ lrank,
                                              uint4* __restrict__ rec,
                                              int N, int E, int CHUNK) {
    __shared__ float s_w[64];
    int t = threadIdx.x;
    if (t < 64) {
        int h = t >> 3, d = t & 7;
        float s = 0.f;
        #pragma unroll
        for (int c = 0; c < HIDC; ++c)
            s += att_edge[h * HIDC + c] * lin_edge_w[(h * HIDC + c) * EDIM + d];
        s_w[t] = s;
    }
    __syncthreads();
    int e = blockIdx.x * 256 + t;
    if (e >= E) return;

    int s = ei[e];
    int d = ei[E + e];
    int pos = part_hist[(size_t)(e / CHUNK) * N + d] + lrank[e];

    float4 ea0 = *(const float4*)(ea + (size_t)e * EDIM);
    float4 ea1 = *(const float4*)(ea + (size_t)e * EDIM + 4);
    float eav[8] = {ea0.x, ea0.y, ea0.z, ea0.w, ea1.x, ea1.y, ea1.z, ea1.w};

    float4 as0 = *(const float4*)(a_src + (size_t)s * NHEAD);
    float4 as1 = *(const float4*)(a_src + (size_t)s * NHEAD + 4);
    float4 ad0 = *(const float4*)(a_dst + (size_t)d * NHEAD);
    float4 ad1 = *(const float4*)(a_dst + (size_t)d * NHEAD + 4);
    float asv[8] = {as0.x, as0.y, as0.z, as0.w, as1.x, as1.y, as1.z, as1.w};
    float adv[8] = {ad0.x, ad0.y, ad0.z, ad0.w, ad1.x, ad1.y, ad1.z, ad1.w};

    float exs[8];
    #pragma unroll
    for (int h = 0; h < NHEAD; ++h) {
        float aev = 0.f;
        #pragma unroll
        for (int dd = 0; dd < EDIM; ++dd) aev += eav[dd] * s_w[h * EDIM + dd];
        float lg = asv[h] + adv[h] + aev;
        lg = (lg >= 0.f) ? lg : 0.2f * lg;
        exs[h] = __expf(lg);
    }
    unsigned int pk[4];
    #pragma unroll
    for (int j = 0; j < 4; ++j) {
        unsigned short lo = __half_as_ushort(__float2half_rn(exs[2 * j]));
        unsigned short hi = __half_as_ushort(__float2half_rn(exs[2 * j + 1]));
        pk[j] = (unsigned int)lo | ((unsigned int)hi << 16);
    }
    rec[(size_t)pos * 2] = make_uint4(pk[0], pk[1], pk[2], pk[3]);
    ((int*)rec)[(size_t)pos * 8 + 4] = s;   // same 64B line as the uint4
}

// ---------------------------------------------------------------------------
// One block (128 thr) per destination node; thread t owns (h,c) = (t>>4,t&15).
__global__ __launch_bounds__(128) void k_gather(const uint4* __restrict__ rec,
                                                const int* __restrict__ start,
                                                const __half* __restrict__ xp_h,
                                                const float* __restrict__ conv_bias,
                                                const float* __restrict__ attn_w,
                                                const float* __restrict__ attn_b,
                                                float* __restrict__ out_feat,
                                                float* __restrict__ score,
                                                float* __restrict__ attn66,
                                                int N) {
    int n = blockIdx.x;
    int t = threadIdx.x;
    int h = t >> 4;

    __shared__ int s_s[128];
    __shared__ float s_ex[128 * NHEAD];
    __shared__ float sred[128];
    __shared__ float sden[NHEAD];

    int s0 = start[n];
    int s1 = start[n + 1];

    float acc = 0.f;
    float den = 0.f;   // lanes with (t&15)==0
    float a66 = 0.f;   // lane 0 of block 6

    for (int base = s0; base < s1; base += 128) {
        int m = s1 - base; if (m > 128) m = 128;
        __syncthreads();
        if (t < m) {
            size_t p = (size_t)(base + t);
            uint4 u = rec[p * 2];
            s_s[t] = ((const int*)rec)[p * 8 + 4];
            float2 f0 = __half22float2(*reinterpret_cast<const __half2*>(&u.x));
            float2 f1 = __half22float2(*reinterpret_cast<const __half2*>(&u.y));
            float2 f2 = __half22float2(*reinterpret_cast<const __half2*>(&u.z));
            float2 f3 = __half22float2(*reinterpret_cast<const __half2*>(&u.w));
            float* row = s_ex + t * NHEAD;
            row[0] = f0.x; row[1] = f0.y; row[2] = f1.x; row[3] = f1.y;
            row[4] = f2.x; row[5] = f2.y; row[6] = f3.x; row[7] = f3.y;
        }
        __syncthreads();
        #pragma unroll 4
        for (int i = 0; i < m; ++i) {
            float ev = s_ex[i * NHEAD + h];
            acc += ev * __half2float(xp_h[(size_t)s_s[i] * HHID + t]);
            if ((t & 15) == 0) den += ev;
            if (t == 0 && n == 6 && s_s[i] == 6) a66 += ev;
        }
    }

    if ((t & 15) == 0) sden[h] = den;
    __syncthreads();
    float inv = 1.f / (sden[h] + 1e-16f);
    acc *= inv;
    if (n == 6 && t == 0) attn66[0] = a66 / (sden[0] + 1e-16f);

    sred[t] = acc;
    __syncthreads();
    if (t < HIDC) {
        float sum = 0.f;
        #pragma unroll
        for (int hh = 0; hh < NHEAD; ++hh) sum += sred[hh * HIDC + t];
        float v = sum * 0.125f + conv_bias[t];
        v = (v > 0.f) ? v : expm1f(v);
        out_feat[n * HIDC + t] = v;
        sred[t] = v * attn_w[t];
    }
    __syncthreads();
    if (t == 0) {
        float sc = 0.f;
        #pragma unroll
        for (int c = 0; c < HIDC; ++c) sc += sred[c];
        score[n] = sc + attn_b[0];
    }
}

// ---------------------------------------------------------------------------
// Final projection, stage 1: per-block partials of the 3 dot products with
// UNSHIFTED softmax weights exp(score[n]) plus psum = sum(exp(score)).
// No atomics: one float4 store per block.
__global__ __launch_bounds__(256) void k_final_part(const float* __restrict__ out_feat,
                                                    const float* __restrict__ score,
                                                    const float* __restrict__ out_w,
                                                    float4* __restrict__ part,
                                                    int N) {
    int total = N * HIDC;
    float p0 = 0.f, p1 = 0.f, p2 = 0.f, ps = 0.f;
    for (int i = blockIdx.x * 256 + threadIdx.x; i < total; i += gridDim.x * 256) {
        int n = i >> 4;
        float w = __expf(score[n]);
        float f = out_feat[i] * w;
        p0 += f * out_w[i];
        p1 += f * out_w[total + i];
        p2 += f * out_w[2 * total + i];
        if ((i & 15) == 0) ps += w;
    }
    #pragma unroll
    for (int off = 32; off > 0; off >>= 1) {
        p0 += __shfl_down(p0, off);
        p1 += __shfl_down(p1, off);
        p2 += __shfl_down(p2, off);
        ps += __shfl_down(ps, off);
    }
    __shared__ float sm[4][4];
    int wid = threadIdx.x >> 6;
    if ((threadIdx.x & 63) == 0) {
        sm[wid][0] = p0; sm[wid][1] = p1; sm[wid][2] = p2; sm[wid][3] = ps;
    }
    __syncthreads();
    if (threadIdx.x == 0) {
        float a = 0.f, b = 0.f, c = 0.f, d = 0.f;
        #pragma unroll
        for (int w2 = 0; w2 < 4; ++w2) {
            a += sm[w2][0]; b += sm[w2][1]; c += sm[w2][2]; d += sm[w2][3];
        }
        part[blockIdx.x] = make_float4(a, b, c, d);
    }
}

// ---------------------------------------------------------------------------
// Final projection, stage 2: sum FB partials, normalize, +bias, write d_out.
__global__ __launch_bounds__(128) void k_final_sum(const float4* __restrict__ part,
                                                   const float* __restrict__ out_b,
                                                   const float* __restrict__ attn66,
                                                   float* __restrict__ d_out) {
    int t = threadIdx.x;
    float4 v = (t < FB) ? part[t] : make_float4(0.f, 0.f, 0.f, 0.f);
    float a = v.x, b = v.y, c = v.z, d = v.w;
    #pragma unroll
    for (int off = 32; off > 0; off >>= 1) {
        a += __shfl_down(a, off);
        b += __shfl_down(b, off);
        c += __shfl_down(c, off);
        d += __shfl_down(d, off);
    }
    __shared__ float4 sm[2];
    if ((t & 63) == 0) sm[t >> 6] = make_float4(a, b, c, d);
    __syncthreads();
    if (t == 0) {
        a = sm[0].x + sm[1].x;
        b = sm[0].y + sm[1].y;
        c = sm[0].z + sm[1].z;
        d = sm[0].w + sm[1].w;
        float inv = 1.f / d;
        d_out[0] = a * inv + out_b[0];
        d_out[1] = b * inv + out_b[1];
        d_out[2] = c * inv + out_b[2];
        d_out[3] = attn66[0];
    }
}

// ---------------------------------------------------------------------------
extern "C" void kernel_launch(void* const* d_in, const int* in_sizes, int n_in,
                              void* d_out, int out_size, void* d_ws, size_t ws_size,
                              hipStream_t stream) {
    const float* x          = (const float*)d_in[0];
    const float* edge_attr  = (const float*)d_in[1];
    const float* fc_w       = (const float*)d_in[2];
    const float* fc_b       = (const float*)d_in[3];
    const float* lin_w      = (const float*)d_in[4];
    const float* att_src    = (const float*)d_in[5];
    const float* att_dst    = (const float*)d_in[6];
    const float* att_edge   = (const float*)d_in[7];
    const float* lin_edge_w = (const float*)d_in[8];
    const float* conv_bias  = (const float*)d_in[9];
    const float* attn_fc_w  = (const float*)d_in[10];
    const float* attn_fc_b  = (const float*)d_in[11];
    const float* out_w      = (const float*)d_in[12];
    const float* out_b      = (const float*)d_in[13];
    const int*   edge_index = (const int*)d_in[14];
    float* out = (float*)d_out;

    const int N = in_sizes[0] / IN_F;
    const int E = in_sizes[14] / 2;
    const int CHUNK = (E + HB - 1) / HB;

    // workspace layout (descending alignment)
    char* w = (char*)d_ws;
    uint4* rec      = (uint4*)w;     w += (size_t)E * 32;          // 20.5 MB
    float4* part    = (float4*)w;    w += (size_t)FB * 16;         //   2 KB
    __half* xp_h    = (__half*)w;    w += (size_t)N * HHID * 2;    //  2.6 MB
    int* part_hist  = (int*)w;       w += (size_t)HB * N * 4;      //  5.1 MB
    int* lrank      = (int*)w;       w += (size_t)E * 4;           //  2.6 MB
    float* a_src    = (float*)w;     w += (size_t)N * NHEAD * 4;
    float* a_dst    = (float*)w;     w += (size_t)N * NHEAD * 4;
    float* out_feat = (float*)w;     w += (size_t)N * HIDC * 4;
    float* score    = (float*)w;     w += (size_t)N * 4;
    float* attn66   = (float*)w;     w += 4;
    int* deg        = (int*)w;       w += (size_t)N * 4;
    int* start      = (int*)w;       w += (size_t)(N + 1) * 4;

    k_node<<<(N + 31) / 32, 256, 0, stream>>>(x, fc_w, fc_b, lin_w, att_src, att_dst,
                                              xp_h, a_src, a_dst, N);
    k_hist<<<HB, 256, 0, stream>>>(edge_index, part_hist, lrank, N, E, CHUNK);
    k_colsum<<<(N + 255) / 256, 256, 0, stream>>>(part_hist, deg, N);
    k_scan<<<1, 1024, 0, stream>>>(deg, start, N);
    k_coloff<<<(N + 255) / 256, 256, 0, stream>>>(part_hist, start, N);
    k_fill<<<(E + 255) / 256, 256, 0, stream>>>(edge_attr, edge_index, a_src, a_dst,
                                                att_edge, lin_edge_w, part_hist, lrank,
                                                rec, N, E, CHUNK);
    k_gather<<<N, 128, 0, stream>>>(rec, start, xp_h, conv_bias,
                                    attn_fc_w, attn_fc_b, out_feat, score, attn66, N);
    k_final_part<<<FB, 256, 0, stream>>>(out_feat, score, out_w, part, N);
    k_final_sum<<<1, 128, 0, stream>>>(part, out_b, attn66, out);
}

// Round 7
// 96.313 us; speedup vs baseline: 51.3183x; 1.1898x over previous
//
#include <hip/hip_runtime.h>
#include <hip/hip_fp16.h>

#define IN_F 128
#define HIDC 16
#define NHEAD 8
#define HHID 128   // NHEAD*HIDC
#define EDIM 8
#define MAXN 10240 // LDS histogram capacity (N=10000)
#define HB   128   // histogram blocks (counting-sort partitions)
#define FB   128   // final-reduction partial blocks

// ---------------------------------------------------------------------------
// Fused block-specialized kernel: blocks [0,HB) build the per-chunk LDS
// histogram + local rank (counting sort phase 1); blocks [HB, HB+NB_NODE)
// do the node transform (h = x@fc_w.T+b; xp = h@lin_w.T -> f16; a_src/a_dst).
__global__ __launch_bounds__(256) void k_node_hist(const float* __restrict__ x,
                                                   const float* __restrict__ fc_w,
                                                   const float* __restrict__ fc_b,
                                                   const float* __restrict__ lin_w,
                                                   const float* __restrict__ att_src,
                                                   const float* __restrict__ att_dst,
                                                   const int* __restrict__ ei,
                                                   __half* __restrict__ xp_h,
                                                   float* __restrict__ a_src,
                                                   float* __restrict__ a_dst,
                                                   int* __restrict__ part_hist,
                                                   int* __restrict__ lrank,
                                                   int N, int E, int CHUNK) {
    __shared__ __align__(16) char smem[MAXN * 4];   // 40 KB union
    int t = threadIdx.x;

    if ((int)blockIdx.x < HB) {
        // ---------------- histogram path ----------------
        int* lh = (int*)smem;
        int b = blockIdx.x;
        for (int i = t; i < MAXN; i += 256) lh[i] = 0;
        __syncthreads();
        int e0 = b * CHUNK;
        int e1 = min(e0 + CHUNK, E);
        for (int e = e0 + t; e < e1; e += 256)
            lrank[e] = atomicAdd(&lh[ei[E + e]], 1);
        __syncthreads();
        for (int nn = t; nn < N; nn += 256) part_hist[(size_t)b * N + nn] = lh[nn];
        return;
    }

    // ---------------- node-transform path ----------------
    float* s_x   = (float*)smem;            // 32*129
    float* s_fc  = s_x + 32 * 129;          // 16*129
    float* s_lin = s_fc + 16 * 129;         // 128*17
    float* s_h   = s_lin + 128 * 17;        // 32*17
    float* s_as  = s_h + 32 * 17;           // 128
    float* s_ad  = s_as + HHID;             // 128
    float* s_fcb = s_ad + HHID;             // 16

    int n0 = (blockIdx.x - HB) * 32;

    for (int i = t; i < HIDC * IN_F; i += 256) s_fc[(i >> 7) * 129 + (i & 127)] = fc_w[i];
    for (int i = t; i < HHID * HIDC; i += 256) s_lin[(i >> 4) * 17 + (i & 15)] = lin_w[i];
    if (t < HHID) { s_as[t] = att_src[t]; s_ad[t] = att_dst[t]; }
    if (t < HIDC) s_fcb[t] = fc_b[t];
    for (int i = t; i < 32 * IN_F; i += 256) {
        size_t g = (size_t)n0 * IN_F + i;
        s_x[(i >> 7) * 129 + (i & 127)] = (g < (size_t)N * IN_F) ? x[g] : 0.f;
    }
    __syncthreads();

    // stage 2: h[n][k], thread handles (k, k+8) for one n
    {
        int k = t >> 5, n_l = t & 31;
        float a0 = 0.f, a1 = 0.f;
        #pragma unroll 8
        for (int d = 0; d < IN_F; ++d) {
            float xv = s_x[n_l * 129 + d];
            a0 += xv * s_fc[k * 129 + d];
            a1 += xv * s_fc[(k + 8) * 129 + d];
        }
        s_h[n_l * 17 + k]     = a0 + s_fcb[k];
        s_h[n_l * 17 + k + 8] = a1 + s_fcb[k + 8];
    }
    __syncthreads();

    // stage 3: thread handles (head, n_l): 16 xp values + as/ad
    int head = t >> 5, n_l = t & 31;
    int n = n0 + n_l;
    if (n >= N) return;

    float hreg[HIDC];
    #pragma unroll
    for (int k = 0; k < HIDC; ++k) hreg[k] = s_h[n_l * 17 + k];

    float as = 0.f, ad = 0.f;
    unsigned int pk[8];
    #pragma unroll
    for (int c2 = 0; c2 < 8; ++c2) {
        float v2[2];
        #pragma unroll
        for (int u = 0; u < 2; ++u) {
            int c = c2 * 2 + u;
            int j = head * HIDC + c;
            float v = 0.f;
            #pragma unroll
            for (int k = 0; k < HIDC; ++k) v += hreg[k] * s_lin[j * 17 + k];
            v2[u] = v;
            as += v * s_as[j];
            ad += v * s_ad[j];
        }
        unsigned short lo = __half_as_ushort(__float2half_rn(v2[0]));
        unsigned short hi = __half_as_ushort(__float2half_rn(v2[1]));
        pk[c2] = (unsigned int)lo | ((unsigned int)hi << 16);
    }
    __half* xph = xp_h + (size_t)n * HHID + head * HIDC;
    *(uint4*)(xph)     = make_uint4(pk[0], pk[1], pk[2], pk[3]);
    *(uint4*)(xph + 8) = make_uint4(pk[4], pk[5], pk[6], pk[7]);
    a_src[n * NHEAD + head] = as;
    a_dst[n * NHEAD + head] = ad;
}

// ---------------------------------------------------------------------------
__global__ __launch_bounds__(256) void k_colsum(const int* __restrict__ part_hist,
                                                int* __restrict__ deg, int N) {
    int n = blockIdx.x * 256 + threadIdx.x;
    if (n >= N) return;
    int s = 0;
    for (int b = 0; b < HB; ++b) s += part_hist[(size_t)b * N + n];
    deg[n] = s;
}

// ---------------------------------------------------------------------------
// Exclusive scan, single block, chunk-per-thread + wave-shuffle (3 barriers).
__global__ __launch_bounds__(1024) void k_scan(const int* __restrict__ deg,
                                               int* __restrict__ start, int N) {
    const int CH = 16;
    __shared__ int s_w[16];
    int t = threadIdx.x;
    int lane = t & 63, wid = t >> 6;
    int vals[CH];
    int base_i = t * CH;
    int s = 0;
    #pragma unroll
    for (int i = 0; i < CH; ++i) {
        int idx = base_i + i;
        int v = (idx < N) ? deg[idx] : 0;
        vals[i] = v;
        s += v;
    }
    int inc = s;
    #pragma unroll
    for (int off = 1; off < 64; off <<= 1) {
        int u = __shfl_up(inc, off, 64);
        if (lane >= off) inc += u;
    }
    if (lane == 63) s_w[wid] = inc;
    __syncthreads();
    if (wid == 0) {
        int wv = (lane < 16) ? s_w[lane] : 0;
        #pragma unroll
        for (int off = 1; off < 16; off <<= 1) {
            int u = __shfl_up(wv, off, 64);
            if (lane >= off) wv += u;
        }
        if (lane < 16) s_w[lane] = wv;
    }
    __syncthreads();
    int base = inc - s + (wid > 0 ? s_w[wid - 1] : 0);
    #pragma unroll
    for (int i = 0; i < CH; ++i) {
        int idx = base_i + i;
        if (idx < N) start[idx] = base;
        base += vals[i];
    }
    if (t == 0) start[N] = s_w[15];
}

// ---------------------------------------------------------------------------
__global__ __launch_bounds__(256) void k_coloff(int* __restrict__ part_hist,
                                                const int* __restrict__ start,
                                                int N) {
    int n = blockIdx.x * 256 + threadIdx.x;
    if (n >= N) return;
    int run = start[n];
    for (int b = 0; b < HB; ++b) {
        size_t idx = (size_t)b * N + n;
        int v = part_hist[idx];
        part_hist[idx] = run;
        run += v;
    }
}

// ---------------------------------------------------------------------------
// Per edge: ex = exp(LeakyReLU(a_src[s]+a_dst[d]+a_edge)); one 32B record
// {ex[8] f16, src} at CSR slot part_hist[b][d] + lrank[e]. No atomics.
__global__ __launch_bounds__(256) void k_fill(const float* __restrict__ ea,
                                              const int* __restrict__ ei,
                                              const float* __restrict__ a_src,
                                              const float* __restrict__ a_dst,
                                              const float* __restrict__ att_edge,
                                              const float* __restrict__ lin_edge_w,
                                              const int* __restrict__ part_hist,
                                              const int* __restrict__ lrank,
                                              uint4* __restrict__ rec,
                                              int N, int E, int CHUNK) {
    __shared__ float s_w[64];
    int t = threadIdx.x;
    if (t < 64) {
        int h = t >> 3, d = t & 7;
        float s = 0.f;
        #pragma unroll
        for (int c = 0; c < HIDC; ++c)
            s += att_edge[h * HIDC + c] * lin_edge_w[(h * HIDC + c) * EDIM + d];
        s_w[t] = s;
    }
    __syncthreads();
    int e = blockIdx.x * 256 + t;
    if (e >= E) return;

    int s = ei[e];
    int d = ei[E + e];
    int pos = part_hist[(size_t)(e / CHUNK) * N + d] + lrank[e];

    float4 ea0 = *(const float4*)(ea + (size_t)e * EDIM);
    float4 ea1 = *(const float4*)(ea + (size_t)e * EDIM + 4);
    float eav[8] = {ea0.x, ea0.y, ea0.z, ea0.w, ea1.x, ea1.y, ea1.z, ea1.w};

    float4 as0 = *(const float4*)(a_src + (size_t)s * NHEAD);
    float4 as1 = *(const float4*)(a_src + (size_t)s * NHEAD + 4);
    float4 ad0 = *(const float4*)(a_dst + (size_t)d * NHEAD);
    float4 ad1 = *(const float4*)(a_dst + (size_t)d * NHEAD + 4);
    float asv[8] = {as0.x, as0.y, as0.z, as0.w, as1.x, as1.y, as1.z, as1.w};
    float adv[8] = {ad0.x, ad0.y, ad0.z, ad0.w, ad1.x, ad1.y, ad1.z, ad1.w};

    float exs[8];
    #pragma unroll
    for (int h = 0; h < NHEAD; ++h) {
        float aev = 0.f;
        #pragma unroll
        for (int dd = 0; dd < EDIM; ++dd) aev += eav[dd] * s_w[h * EDIM + dd];
        float lg = asv[h] + adv[h] + aev;
        lg = (lg >= 0.f) ? lg : 0.2f * lg;
        exs[h] = __expf(lg);
    }
    unsigned int pk[4];
    #pragma unroll
    for (int j = 0; j < 4; ++j) {
        unsigned short lo = __half_as_ushort(__float2half_rn(exs[2 * j]));
        unsigned short hi = __half_as_ushort(__float2half_rn(exs[2 * j + 1]));
        pk[j] = (unsigned int)lo | ((unsigned int)hi << 16);
    }
    rec[(size_t)pos * 2] = make_uint4(pk[0], pk[1], pk[2], pk[3]);
    ((int*)rec)[(size_t)pos * 8 + 4] = s;   // same 64B line as the uint4
}

// ---------------------------------------------------------------------------
// One block (128 thr) per destination node. Vectorized gather: thread
// (es,v) = (t>>4, t&15) loads uint4 = 8 halves (components j = 8v..8v+7,
// all in head h = v>>1) of edge i+es. acc8[8] partials reduced across the
// 8 es-groups via LDS at the end. 8 edges per block-wide load instruction.
__global__ __launch_bounds__(128) void k_gather(const uint4* __restrict__ rec,
                                                const int* __restrict__ start,
                                                const __half* __restrict__ xp_h,
                                                const float* __restrict__ conv_bias,
                                                const float* __restrict__ attn_w,
                                                const float* __restrict__ attn_b,
                                                float* __restrict__ out_feat,
                                                float* __restrict__ score,
                                                float* __restrict__ attn66,
                                                int N) {
    int n = blockIdx.x;
    int t = threadIdx.x;
    int es = t >> 4;        // 0..7 edge subgroup
    int v  = t & 15;        // uint4 index within the 128-half row
    int hv = v >> 1;        // head owned by this thread's components

    __shared__ int s_s[128];
    __shared__ float s_ex[128 * NHEAD];
    __shared__ float sacc[8 * 128];
    __shared__ float sdenp[128];
    __shared__ float sden[NHEAD];
    __shared__ float sred[128];

    int s0 = start[n];
    int s1 = start[n + 1];

    float acc8[8];
    #pragma unroll
    for (int k = 0; k < 8; ++k) acc8[k] = 0.f;
    float denp = 0.f;       // partial denom: head t>>4, edge slots i%16 == t&15
    float a66 = 0.f;

    for (int base = s0; base < s1; base += 128) {
        int m = s1 - base; if (m > 128) m = 128;
        __syncthreads();
        if (t < m) {
            size_t p = (size_t)(base + t);
            uint4 u = rec[p * 2];
            s_s[t] = ((const int*)rec)[p * 8 + 4];
            float2 f0 = __half22float2(*reinterpret_cast<const __half2*>(&u.x));
            float2 f1 = __half22float2(*reinterpret_cast<const __half2*>(&u.y));
            float2 f2 = __half22float2(*reinterpret_cast<const __half2*>(&u.z));
            float2 f3 = __half22float2(*reinterpret_cast<const __half2*>(&u.w));
            float* row = s_ex + t * NHEAD;
            row[0] = f0.x; row[1] = f0.y; row[2] = f1.x; row[3] = f1.y;
            row[4] = f2.x; row[5] = f2.y; row[6] = f3.x; row[7] = f3.y;
        }
        __syncthreads();
        // main accumulation: 8 edges per iteration, 16B per thread
        #pragma unroll 2
        for (int i = 0; i < m; i += 8) {
            int e_i = i + es;
            if (e_i < m) {
                const uint4 u = *(const uint4*)(xp_h + (size_t)s_s[e_i] * HHID + v * 8);
                float ev = s_ex[e_i * NHEAD + hv];
                float2 f0 = __half22float2(*reinterpret_cast<const __half2*>(&u.x));
                float2 f1 = __half22float2(*reinterpret_cast<const __half2*>(&u.y));
                float2 f2 = __half22float2(*reinterpret_cast<const __half2*>(&u.z));
                float2 f3 = __half22float2(*reinterpret_cast<const __half2*>(&u.w));
                acc8[0] += ev * f0.x; acc8[1] += ev * f0.y;
                acc8[2] += ev * f1.x; acc8[3] += ev * f1.y;
                acc8[4] += ev * f2.x; acc8[5] += ev * f2.y;
                acc8[6] += ev * f3.x; acc8[7] += ev * f3.y;
            }
        }
        // denominator partials: thread t covers head t>>4, edges i%16==t&15
        {
            int hh = t >> 4, sl = t & 15;
            for (int i = sl; i < m; i += 16) denp += s_ex[i * NHEAD + hh];
        }
        // attn66 (node 6 only): serial scan by thread 0
        if (n == 6 && t == 0) {
            for (int i = 0; i < m; ++i)
                if (s_s[i] == 6) a66 += s_ex[i * NHEAD];
        }
    }

    // cross-group reduction
    sdenp[t] = denp;
    #pragma unroll
    for (int k = 0; k < 8; ++k) sacc[es * 128 + v * 8 + k] = acc8[k];
    __syncthreads();
    if (t < NHEAD) {
        float dsum = 0.f;
        #pragma unroll
        for (int sl = 0; sl < 16; ++sl) dsum += sdenp[t * 16 + sl];
        sden[t] = dsum;
    }
    __syncthreads();

    float accv = 0.f;
    #pragma unroll
    for (int g = 0; g < 8; ++g) accv += sacc[g * 128 + t];
    accv *= 1.f / (sden[t >> 4] + 1e-16f);
    if (n == 6 && t == 0) attn66[0] = a66 / (sden[0] + 1e-16f);

    sred[t] = accv;
    __syncthreads();
    if (t < HIDC) {
        float sum = 0.f;
        #pragma unroll
        for (int hh = 0; hh < NHEAD; ++hh) sum += sred[hh * HIDC + t];
        float vv = sum * 0.125f + conv_bias[t];
        vv = (vv > 0.f) ? vv : expm1f(vv);
        out_feat[n * HIDC + t] = vv;
        sred[t] = vv * attn_w[t];
    }
    __syncthreads();
    if (t == 0) {
        float sc = 0.f;
        #pragma unroll
        for (int c = 0; c < HIDC; ++c) sc += sred[c];
        score[n] = sc + attn_b[0];
    }
}

// ---------------------------------------------------------------------------
// Final projection, stage 1: per-block partials of the 3 dot products with
// UNSHIFTED softmax weights exp(score[n]) plus psum = sum(exp(score)).
__global__ __launch_bounds__(256) void k_final_part(const float* __restrict__ out_feat,
                                                    const float* __restrict__ score,
                                                    const float* __restrict__ out_w,
                                                    float4* __restrict__ part,
                                                    int N) {
    int total = N * HIDC;
    float p0 = 0.f, p1 = 0.f, p2 = 0.f, ps = 0.f;
    for (int i = blockIdx.x * 256 + threadIdx.x; i < total; i += gridDim.x * 256) {
        int n = i >> 4;
        float w = __expf(score[n]);
        float f = out_feat[i] * w;
        p0 += f * out_w[i];
        p1 += f * out_w[total + i];
        p2 += f * out_w[2 * total + i];
        if ((i & 15) == 0) ps += w;
    }
    #pragma unroll
    for (int off = 32; off > 0; off >>= 1) {
        p0 += __shfl_down(p0, off);
        p1 += __shfl_down(p1, off);
        p2 += __shfl_down(p2, off);
        ps += __shfl_down(ps, off);
    }
    __shared__ float sm[4][4];
    int wid = threadIdx.x >> 6;
    if ((threadIdx.x & 63) == 0) {
        sm[wid][0] = p0; sm[wid][1] = p1; sm[wid][2] = p2; sm[wid][3] = ps;
    }
    __syncthreads();
    if (threadIdx.x == 0) {
        float a = 0.f, b = 0.f, c = 0.f, d = 0.f;
        #pragma unroll
        for (int w2 = 0; w2 < 4; ++w2) {
            a += sm[w2][0]; b += sm[w2][1]; c += sm[w2][2]; d += sm[w2][3];
        }
        part[blockIdx.x] = make_float4(a, b, c, d);
    }
}

// ---------------------------------------------------------------------------
__global__ __launch_bounds__(128) void k_final_sum(const float4* __restrict__ part,
                                                   const float* __restrict__ out_b,
                                                   const float* __restrict__ attn66,
                                                   float* __restrict__ d_out) {
    int t = threadIdx.x;
    float4 v = (t < FB) ? part[t] : make_float4(0.f, 0.f, 0.f, 0.f);
    float a = v.x, b = v.y, c = v.z, d = v.w;
    #pragma unroll
    for (int off = 32; off > 0; off >>= 1) {
        a += __shfl_down(a, off);
        b += __shfl_down(b, off);
        c += __shfl_down(c, off);
        d += __shfl_down(d, off);
    }
    __shared__ float4 sm[2];
    if ((t & 63) == 0) sm[t >> 6] = make_float4(a, b, c, d);
    __syncthreads();
    if (t == 0) {
        a = sm[0].x + sm[1].x;
        b = sm[0].y + sm[1].y;
        c = sm[0].z + sm[1].z;
        d = sm[0].w + sm[1].w;
        float inv = 1.f / d;
        d_out[0] = a * inv + out_b[0];
        d_out[1] = b * inv + out_b[1];
        d_out[2] = c * inv + out_b[2];
        d_out[3] = attn66[0];
    }
}

// ---------------------------------------------------------------------------
extern "C" void kernel_launch(void* const* d_in, const int* in_sizes, int n_in,
                              void* d_out, int out_size, void* d_ws, size_t ws_size,
                              hipStream_t stream) {
    const float* x          = (const float*)d_in[0];
    const float* edge_attr  = (const float*)d_in[1];
    const float* fc_w       = (const float*)d_in[2];
    const float* fc_b       = (const float*)d_in[3];
    const float* lin_w      = (const float*)d_in[4];
    const float* att_src    = (const float*)d_in[5];
    const float* att_dst    = (const float*)d_in[6];
    const float* att_edge   = (const float*)d_in[7];
    const float* lin_edge_w = (const float*)d_in[8];
    const float* conv_bias  = (const float*)d_in[9];
    const float* attn_fc_w  = (const float*)d_in[10];
    const float* attn_fc_b  = (const float*)d_in[11];
    const float* out_w      = (const float*)d_in[12];
    const float* out_b      = (const float*)d_in[13];
    const int*   edge_index = (const int*)d_in[14];
    float* out = (float*)d_out;

    const int N = in_sizes[0] / IN_F;
    const int E = in_sizes[14] / 2;
    const int CHUNK = (E + HB - 1) / HB;

    // workspace layout (descending alignment)
    char* w = (char*)d_ws;
    uint4* rec      = (uint4*)w;     w += (size_t)E * 32;          // 20.5 MB
    float4* part    = (float4*)w;    w += (size_t)FB * 16;         //   2 KB
    __half* xp_h    = (__half*)w;    w += (size_t)N * HHID * 2;    //  2.6 MB
    int* part_hist  = (int*)w;       w += (size_t)HB * N * 4;      //  5.1 MB
    int* lrank      = (int*)w;       w += (size_t)E * 4;           //  2.6 MB
    float* a_src    = (float*)w;     w += (size_t)N * NHEAD * 4;
    float* a_dst    = (float*)w;     w += (size_t)N * NHEAD * 4;
    float* out_feat = (float*)w;     w += (size_t)N * HIDC * 4;
    float* score    = (float*)w;     w += (size_t)N * 4;
    float* attn66   = (float*)w;     w += 4;
    int* deg        = (int*)w;       w += (size_t)N * 4;
    int* start      = (int*)w;       w += (size_t)(N + 1) * 4;

    const int NB_NODE = (N + 31) / 32;
    k_node_hist<<<HB + NB_NODE, 256, 0, stream>>>(
        x, fc_w, fc_b, lin_w, att_src, att_dst, edge_index,
        xp_h, a_src, a_dst, part_hist, lrank, N, E, CHUNK);
    k_colsum<<<(N + 255) / 256, 256, 0, stream>>>(part_hist, deg, N);
    k_scan<<<1, 1024, 0, stream>>>(deg, start, N);
    k_coloff<<<(N + 255) / 256, 256, 0, stream>>>(part_hist, start, N);
    k_fill<<<(E + 255) / 256, 256, 0, stream>>>(edge_attr, edge_index, a_src, a_dst,
                                                att_edge, lin_edge_w, part_hist, lrank,
                                                rec, N, E, CHUNK);
    k_gather<<<N, 128, 0, stream>>>(rec, start, xp_h, conv_bias,
                                    attn_fc_w, attn_fc_b, out_feat, score, attn66, N);
    k_final_part<<<FB, 256, 0, stream>>>(out_feat, score, out_w, part, N);
    k_final_sum<<<1, 128, 0, stream>>>(part, out_b, attn66, out);
}

// Round 8
// 81.151 us; speedup vs baseline: 60.9064x; 1.1868x over previous
//
#include <hip/hip_runtime.h>
#include <hip/hip_fp16.h>

#define IN_F 128
#define HIDC 16
#define NHEAD 8
#define HHID 128   // NHEAD*HIDC
#define EDIM 8
#define MAXN 10240 // LDS histogram capacity (N=10000)
#define HB   64    // histogram blocks (counting-sort partitions)
#define FB   128   // final-reduction partial blocks

// ---------------------------------------------------------------------------
// Fused block-specialized kernel: blocks [0,HB) build the per-chunk LDS
// histogram + local rank (counting sort phase 1); blocks [HB, HB+NB_NODE)
// do the node transform (h = x@fc_w.T+b; xp = h@lin_w.T -> f16; a_src/a_dst).
__global__ __launch_bounds__(256) void k_node_hist(const float* __restrict__ x,
                                                   const float* __restrict__ fc_w,
                                                   const float* __restrict__ fc_b,
                                                   const float* __restrict__ lin_w,
                                                   const float* __restrict__ att_src,
                                                   const float* __restrict__ att_dst,
                                                   const int* __restrict__ ei,
                                                   __half* __restrict__ xp_h,
                                                   float* __restrict__ a_src,
                                                   float* __restrict__ a_dst,
                                                   unsigned short* __restrict__ ph,
                                                   unsigned short* __restrict__ lrank,
                                                   int N, int E, int CHUNK) {
    __shared__ __align__(16) char smem[MAXN * 4];   // 40 KB union
    int t = threadIdx.x;

    if ((int)blockIdx.x < HB) {
        // ---------------- histogram path ----------------
        int* lh = (int*)smem;
        int b = blockIdx.x;
        for (int i = t; i < MAXN; i += 256) lh[i] = 0;
        __syncthreads();
        int e0 = b * CHUNK;
        int e1 = min(e0 + CHUNK, E);
        for (int e = e0 + t; e < e1; e += 256)
            lrank[e] = (unsigned short)atomicAdd(&lh[ei[E + e]], 1);
        __syncthreads();
        for (int nn = t; nn < N; nn += 256)
            ph[(size_t)b * N + nn] = (unsigned short)lh[nn];
        return;
    }

    // ---------------- node-transform path ----------------
    float* s_x   = (float*)smem;            // 32*129
    float* s_fc  = s_x + 32 * 129;          // 16*129
    float* s_lin = s_fc + 16 * 129;         // 128*17
    float* s_h   = s_lin + 128 * 17;        // 32*17
    float* s_as  = s_h + 32 * 17;           // 128
    float* s_ad  = s_as + HHID;             // 128
    float* s_fcb = s_ad + HHID;             // 16

    int n0 = (blockIdx.x - HB) * 32;

    for (int i = t; i < HIDC * IN_F; i += 256) s_fc[(i >> 7) * 129 + (i & 127)] = fc_w[i];
    for (int i = t; i < HHID * HIDC; i += 256) s_lin[(i >> 4) * 17 + (i & 15)] = lin_w[i];
    if (t < HHID) { s_as[t] = att_src[t]; s_ad[t] = att_dst[t]; }
    if (t < HIDC) s_fcb[t] = fc_b[t];
    for (int i = t; i < 32 * IN_F; i += 256) {
        size_t g = (size_t)n0 * IN_F + i;
        s_x[(i >> 7) * 129 + (i & 127)] = (g < (size_t)N * IN_F) ? x[g] : 0.f;
    }
    __syncthreads();

    // stage 2: h[n][k], thread handles (k, k+8) for one n
    {
        int k = t >> 5, n_l = t & 31;
        float a0 = 0.f, a1 = 0.f;
        #pragma unroll 8
        for (int d = 0; d < IN_F; ++d) {
            float xv = s_x[n_l * 129 + d];
            a0 += xv * s_fc[k * 129 + d];
            a1 += xv * s_fc[(k + 8) * 129 + d];
        }
        s_h[n_l * 17 + k]     = a0 + s_fcb[k];
        s_h[n_l * 17 + k + 8] = a1 + s_fcb[k + 8];
    }
    __syncthreads();

    // stage 3: thread handles (head, n_l): 16 xp values + as/ad
    int head = t >> 5, n_l = t & 31;
    int n = n0 + n_l;
    if (n >= N) return;

    float hreg[HIDC];
    #pragma unroll
    for (int k = 0; k < HIDC; ++k) hreg[k] = s_h[n_l * 17 + k];

    float as = 0.f, ad = 0.f;
    unsigned int pk[8];
    #pragma unroll
    for (int c2 = 0; c2 < 8; ++c2) {
        float v2[2];
        #pragma unroll
        for (int u = 0; u < 2; ++u) {
            int c = c2 * 2 + u;
            int j = head * HIDC + c;
            float v = 0.f;
            #pragma unroll
            for (int k = 0; k < HIDC; ++k) v += hreg[k] * s_lin[j * 17 + k];
            v2[u] = v;
            as += v * s_as[j];
            ad += v * s_ad[j];
        }
        unsigned short lo = __half_as_ushort(__float2half_rn(v2[0]));
        unsigned short hi = __half_as_ushort(__float2half_rn(v2[1]));
        pk[c2] = (unsigned int)lo | ((unsigned int)hi << 16);
    }
    __half* xph = xp_h + (size_t)n * HHID + head * HIDC;
    *(uint4*)(xph)     = make_uint4(pk[0], pk[1], pk[2], pk[3]);
    *(uint4*)(xph + 8) = make_uint4(pk[4], pk[5], pk[6], pk[7]);
    a_src[n * NHEAD + head] = as;
    a_dst[n * NHEAD + head] = ad;
}

// ---------------------------------------------------------------------------
// Column exclusive prefix (within column n over the HB chunks), in place.
// Loads all HB counts into registers first (pipelined, no serial chain),
// prefixes in-register, stores back, and writes the column total to deg[n].
__global__ __launch_bounds__(256) void k_coloff0(unsigned short* __restrict__ ph,
                                                 int* __restrict__ deg, int N) {
    int n = blockIdx.x * 256 + threadIdx.x;
    if (n >= N) return;
    unsigned short v[HB];
    #pragma unroll
    for (int b = 0; b < HB; ++b) v[b] = ph[(size_t)b * N + n];
    int run = 0;
    #pragma unroll
    for (int b = 0; b < HB; ++b) {
        int c = v[b];
        ph[(size_t)b * N + n] = (unsigned short)run;
        run += c;
    }
    deg[n] = run;
}

// ---------------------------------------------------------------------------
// Exclusive scan, single block, chunk-per-thread + wave-shuffle (3 barriers).
__global__ __launch_bounds__(1024) void k_scan(const int* __restrict__ deg,
                                               int* __restrict__ start, int N) {
    const int CH = 16;
    __shared__ int s_w[16];
    int t = threadIdx.x;
    int lane = t & 63, wid = t >> 6;
    int vals[CH];
    int base_i = t * CH;
    int s = 0;
    #pragma unroll
    for (int i = 0; i < CH; ++i) {
        int idx = base_i + i;
        int v = (idx < N) ? deg[idx] : 0;
        vals[i] = v;
        s += v;
    }
    int inc = s;
    #pragma unroll
    for (int off = 1; off < 64; off <<= 1) {
        int u = __shfl_up(inc, off, 64);
        if (lane >= off) inc += u;
    }
    if (lane == 63) s_w[wid] = inc;
    __syncthreads();
    if (wid == 0) {
        int wv = (lane < 16) ? s_w[lane] : 0;
        #pragma unroll
        for (int off = 1; off < 16; off <<= 1) {
            int u = __shfl_up(wv, off, 64);
            if (lane >= off) wv += u;
        }
        if (lane < 16) s_w[lane] = wv;
    }
    __syncthreads();
    int base = inc - s + (wid > 0 ? s_w[wid - 1] : 0);
    #pragma unroll
    for (int i = 0; i < CH; ++i) {
        int idx = base_i + i;
        if (idx < N) start[idx] = base;
        base += vals[i];
    }
    if (t == 0) start[N] = s_w[15];
}

// ---------------------------------------------------------------------------
// Per edge: ex = exp(LeakyReLU(a_src[s]+a_dst[d]+a_edge)); one 32B record
// {ex[8] f16, src} at CSR slot start[d] + ph[b][d] + lrank[e]. No atomics.
__global__ __launch_bounds__(256) void k_fill(const float* __restrict__ ea,
                                              const int* __restrict__ ei,
                                              const float* __restrict__ a_src,
                                              const float* __restrict__ a_dst,
                                              const float* __restrict__ att_edge,
                                              const float* __restrict__ lin_edge_w,
                                              const int* __restrict__ start,
                                              const unsigned short* __restrict__ ph,
                                              const unsigned short* __restrict__ lrank,
                                              uint4* __restrict__ rec,
                                              int N, int E, int CHUNK) {
    __shared__ float s_w[64];
    int t = threadIdx.x;
    if (t < 64) {
        int h = t >> 3, d = t & 7;
        float s = 0.f;
        #pragma unroll
        for (int c = 0; c < HIDC; ++c)
            s += att_edge[h * HIDC + c] * lin_edge_w[(h * HIDC + c) * EDIM + d];
        s_w[t] = s;
    }
    __syncthreads();
    int e = blockIdx.x * 256 + t;
    if (e >= E) return;

    int s = ei[e];
    int d = ei[E + e];
    int pos = start[d] + (int)ph[(size_t)(e / CHUNK) * N + d] + (int)lrank[e];

    float4 ea0 = *(const float4*)(ea + (size_t)e * EDIM);
    float4 ea1 = *(const float4*)(ea + (size_t)e * EDIM + 4);
    float eav[8] = {ea0.x, ea0.y, ea0.z, ea0.w, ea1.x, ea1.y, ea1.z, ea1.w};

    float4 as0 = *(const float4*)(a_src + (size_t)s * NHEAD);
    float4 as1 = *(const float4*)(a_src + (size_t)s * NHEAD + 4);
    float4 ad0 = *(const float4*)(a_dst + (size_t)d * NHEAD);
    float4 ad1 = *(const float4*)(a_dst + (size_t)d * NHEAD + 4);
    float asv[8] = {as0.x, as0.y, as0.z, as0.w, as1.x, as1.y, as1.z, as1.w};
    float adv[8] = {ad0.x, ad0.y, ad0.z, ad0.w, ad1.x, ad1.y, ad1.z, ad1.w};

    float exs[8];
    #pragma unroll
    for (int h = 0; h < NHEAD; ++h) {
        float aev = 0.f;
        #pragma unroll
        for (int dd = 0; dd < EDIM; ++dd) aev += eav[dd] * s_w[h * EDIM + dd];
        float lg = asv[h] + adv[h] + aev;
        lg = (lg >= 0.f) ? lg : 0.2f * lg;
        exs[h] = __expf(lg);
    }
    unsigned int pk[4];
    #pragma unroll
    for (int j = 0; j < 4; ++j) {
        unsigned short lo = __half_as_ushort(__float2half_rn(exs[2 * j]));
        unsigned short hi = __half_as_ushort(__float2half_rn(exs[2 * j + 1]));
        pk[j] = (unsigned int)lo | ((unsigned int)hi << 16);
    }
    rec[(size_t)pos * 2] = make_uint4(pk[0], pk[1], pk[2], pk[3]);
    ((int*)rec)[(size_t)pos * 8 + 4] = s;   // same 64B line as the uint4
}

// ---------------------------------------------------------------------------
// One block (128 thr) per destination node. Vectorized gather: thread
// (es,v) = (t>>4, t&15) loads uint4 = 8 halves (components j = 8v..8v+7,
// all in head h = v>>1) of edge i+es. acc8[8] partials reduced across the
// 8 es-groups via LDS at the end. 8 edges per block-wide load instruction.
__global__ __launch_bounds__(128) void k_gather(const uint4* __restrict__ rec,
                                                const int* __restrict__ start,
                                                const __half* __restrict__ xp_h,
                                                const float* __restrict__ conv_bias,
                                                const float* __restrict__ attn_w,
                                                const float* __restrict__ attn_b,
                                                float* __restrict__ out_feat,
                                                float* __restrict__ score,
                                                float* __restrict__ attn66,
                                                int N) {
    int n = blockIdx.x;
    int t = threadIdx.x;
    int es = t >> 4;        // 0..7 edge subgroup
    int v  = t & 15;        // uint4 index within the 128-half row
    int hv = v >> 1;        // head owned by this thread's components

    __shared__ int s_s[128];
    __shared__ float s_ex[128 * NHEAD];
    __shared__ float sacc[8 * 128];
    __shared__ float sdenp[128];
    __shared__ float sden[NHEAD];
    __shared__ float sred[128];

    int s0 = start[n];
    int s1 = start[n + 1];

    float acc8[8];
    #pragma unroll
    for (int k = 0; k < 8; ++k) acc8[k] = 0.f;
    float denp = 0.f;       // partial denom: head t>>4, edge slots i%16 == t&15
    float a66 = 0.f;

    for (int base = s0; base < s1; base += 128) {
        int m = s1 - base; if (m > 128) m = 128;
        __syncthreads();
        if (t < m) {
            size_t p = (size_t)(base + t);
            uint4 u = rec[p * 2];
            s_s[t] = ((const int*)rec)[p * 8 + 4];
            float2 f0 = __half22float2(*reinterpret_cast<const __half2*>(&u.x));
            float2 f1 = __half22float2(*reinterpret_cast<const __half2*>(&u.y));
            float2 f2 = __half22float2(*reinterpret_cast<const __half2*>(&u.z));
            float2 f3 = __half22float2(*reinterpret_cast<const __half2*>(&u.w));
            float* row = s_ex + t * NHEAD;
            row[0] = f0.x; row[1] = f0.y; row[2] = f1.x; row[3] = f1.y;
            row[4] = f2.x; row[5] = f2.y; row[6] = f3.x; row[7] = f3.y;
        }
        __syncthreads();
        // main accumulation: 8 edges per iteration, 16B per thread
        #pragma unroll 2
        for (int i = 0; i < m; i += 8) {
            int e_i = i + es;
            if (e_i < m) {
                const uint4 u = *(const uint4*)(xp_h + (size_t)s_s[e_i] * HHID + v * 8);
                float ev = s_ex[e_i * NHEAD + hv];
                float2 f0 = __half22float2(*reinterpret_cast<const __half2*>(&u.x));
                float2 f1 = __half22float2(*reinterpret_cast<const __half2*>(&u.y));
                float2 f2 = __half22float2(*reinterpret_cast<const __half2*>(&u.z));
                float2 f3 = __half22float2(*reinterpret_cast<const __half2*>(&u.w));
                acc8[0] += ev * f0.x; acc8[1] += ev * f0.y;
                acc8[2] += ev * f1.x; acc8[3] += ev * f1.y;
                acc8[4] += ev * f2.x; acc8[5] += ev * f2.y;
                acc8[6] += ev * f3.x; acc8[7] += ev * f3.y;
            }
        }
        // denominator partials: thread t covers head t>>4, edges i%16==t&15
        {
            int hh = t >> 4, sl = t & 15;
            for (int i = sl; i < m; i += 16) denp += s_ex[i * NHEAD + hh];
        }
        // attn66 (node 6 only): serial scan by thread 0
        if (n == 6 && t == 0) {
            for (int i = 0; i < m; ++i)
                if (s_s[i] == 6) a66 += s_ex[i * NHEAD];
        }
    }

    // cross-group reduction
    sdenp[t] = denp;
    #pragma unroll
    for (int k = 0; k < 8; ++k) sacc[es * 128 + v * 8 + k] = acc8[k];
    __syncthreads();
    if (t < NHEAD) {
        float dsum = 0.f;
        #pragma unroll
        for (int sl = 0; sl < 16; ++sl) dsum += sdenp[t * 16 + sl];
        sden[t] = dsum;
    }
    __syncthreads();

    float accv = 0.f;
    #pragma unroll
    for (int g = 0; g < 8; ++g) accv += sacc[g * 128 + t];
    accv *= 1.f / (sden[t >> 4] + 1e-16f);
    if (n == 6 && t == 0) attn66[0] = a66 / (sden[0] + 1e-16f);

    sred[t] = accv;
    __syncthreads();
    if (t < HIDC) {
        float sum = 0.f;
        #pragma unroll
        for (int hh = 0; hh < NHEAD; ++hh) sum += sred[hh * HIDC + t];
        float vv = sum * 0.125f + conv_bias[t];
        vv = (vv > 0.f) ? vv : expm1f(vv);
        out_feat[n * HIDC + t] = vv;
        sred[t] = vv * attn_w[t];
    }
    __syncthreads();
    if (t == 0) {
        float sc = 0.f;
        #pragma unroll
        for (int c = 0; c < HIDC; ++c) sc += sred[c];
        score[n] = sc + attn_b[0];
    }
}

// ---------------------------------------------------------------------------
// Final projection, stage 1: per-block partials of the 3 dot products with
// UNSHIFTED softmax weights exp(score[n]) plus psum = sum(exp(score)).
__global__ __launch_bounds__(256) void k_final_part(const float* __restrict__ out_feat,
                                                    const float* __restrict__ score,
                                                    const float* __restrict__ out_w,
                                                    float4* __restrict__ part,
                                                    int N) {
    int total = N * HIDC;
    float p0 = 0.f, p1 = 0.f, p2 = 0.f, ps = 0.f;
    for (int i = blockIdx.x * 256 + threadIdx.x; i < total; i += gridDim.x * 256) {
        int n = i >> 4;
        float w = __expf(score[n]);
        float f = out_feat[i] * w;
        p0 += f * out_w[i];
        p1 += f * out_w[total + i];
        p2 += f * out_w[2 * total + i];
        if ((i & 15) == 0) ps += w;
    }
    #pragma unroll
    for (int off = 32; off > 0; off >>= 1) {
        p0 += __shfl_down(p0, off);
        p1 += __shfl_down(p1, off);
        p2 += __shfl_down(p2, off);
        ps += __shfl_down(ps, off);
    }
    __shared__ float sm[4][4];
    int wid = threadIdx.x >> 6;
    if ((threadIdx.x & 63) == 0) {
        sm[wid][0] = p0; sm[wid][1] = p1; sm[wid][2] = p2; sm[wid][3] = ps;
    }
    __syncthreads();
    if (threadIdx.x == 0) {
        float a = 0.f, b = 0.f, c = 0.f, d = 0.f;
        #pragma unroll
        for (int w2 = 0; w2 < 4; ++w2) {
            a += sm[w2][0]; b += sm[w2][1]; c += sm[w2][2]; d += sm[w2][3];
        }
        part[blockIdx.x] = make_float4(a, b, c, d);
    }
}

// ---------------------------------------------------------------------------
__global__ __launch_bounds__(128) void k_final_sum(const float4* __restrict__ part,
                                                   const float* __restrict__ out_b,
                                                   const float* __restrict__ attn66,
                                                   float* __restrict__ d_out) {
    int t = threadIdx.x;
    float4 v = (t < FB) ? part[t] : make_float4(0.f, 0.f, 0.f, 0.f);
    float a = v.x, b = v.y, c = v.z, d = v.w;
    #pragma unroll
    for (int off = 32; off > 0; off >>= 1) {
        a += __shfl_down(a, off);
        b += __shfl_down(b, off);
        c += __shfl_down(c, off);
        d += __shfl_down(d, off);
    }
    __shared__ float4 sm[2];
    if ((t & 63) == 0) sm[t >> 6] = make_float4(a, b, c, d);
    __syncthreads();
    if (t == 0) {
        a = sm[0].x + sm[1].x;
        b = sm[0].y + sm[1].y;
        c = sm[0].z + sm[1].z;
        d = sm[0].w + sm[1].w;
        float inv = 1.f / d;
        d_out[0] = a * inv + out_b[0];
        d_out[1] = b * inv + out_b[1];
        d_out[2] = c * inv + out_b[2];
        d_out[3] = attn66[0];
    }
}

// ---------------------------------------------------------------------------
extern "C" void kernel_launch(void* const* d_in, const int* in_sizes, int n_in,
                              void* d_out, int out_size, void* d_ws, size_t ws_size,
                              hipStream_t stream) {
    const float* x          = (const float*)d_in[0];
    const float* edge_attr  = (const float*)d_in[1];
    const float* fc_w       = (const float*)d_in[2];
    const float* fc_b       = (const float*)d_in[3];
    const float* lin_w      = (const float*)d_in[4];
    const float* att_src    = (const float*)d_in[5];
    const float* att_dst    = (const float*)d_in[6];
    const float* att_edge   = (const float*)d_in[7];
    const float* lin_edge_w = (const float*)d_in[8];
    const float* conv_bias  = (const float*)d_in[9];
    const float* attn_fc_w  = (const float*)d_in[10];
    const float* attn_fc_b  = (const float*)d_in[11];
    const float* out_w      = (const float*)d_in[12];
    const float* out_b      = (const float*)d_in[13];
    const int*   edge_index = (const int*)d_in[14];
    float* out = (float*)d_out;

    const int N = in_sizes[0] / IN_F;
    const int E = in_sizes[14] / 2;
    const int CHUNK = (E + HB - 1) / HB;

    // workspace layout (descending alignment)
    char* w = (char*)d_ws;
    uint4* rec      = (uint4*)w;           w += (size_t)E * 32;        // 20.5 MB
    float4* part    = (float4*)w;          w += (size_t)FB * 16;       //   2 KB
    __half* xp_h    = (__half*)w;          w += (size_t)N * HHID * 2;  //  2.6 MB
    float* a_src    = (float*)w;           w += (size_t)N * NHEAD * 4;
    float* a_dst    = (float*)w;           w += (size_t)N * NHEAD * 4;
    float* out_feat = (float*)w;           w += (size_t)N * HIDC * 4;
    float* score    = (float*)w;           w += (size_t)N * 4;
    float* attn66   = (float*)w;           w += 4;
    int* deg        = (int*)w;             w += (size_t)N * 4;
    int* start      = (int*)w;             w += (size_t)(N + 1) * 4;
    unsigned short* ph    = (unsigned short*)w; w += (size_t)HB * N * 2;  // 1.28 MB
    unsigned short* lrank = (unsigned short*)w; w += (size_t)E * 2;       // 1.3 MB

    const int NB_NODE = (N + 31) / 32;
    k_node_hist<<<HB + NB_NODE, 256, 0, stream>>>(
        x, fc_w, fc_b, lin_w, att_src, att_dst, edge_index,
        xp_h, a_src, a_dst, ph, lrank, N, E, CHUNK);
    k_coloff0<<<(N + 255) / 256, 256, 0, stream>>>(ph, deg, N);
    k_scan<<<1, 1024, 0, stream>>>(deg, start, N);
    k_fill<<<(E + 255) / 256, 256, 0, stream>>>(edge_attr, edge_index, a_src, a_dst,
                                                att_edge, lin_edge_w, start, ph, lrank,
                                                rec, N, E, CHUNK);
    k_gather<<<N, 128, 0, stream>>>(rec, start, xp_h, conv_bias,
                                    attn_fc_w, attn_fc_b, out_feat, score, attn66, N);
    k_final_part<<<FB, 256, 0, stream>>>(out_feat, score, out_w, part, N);
    k_final_sum<<<1, 128, 0, stream>>>(part, out_b, attn66, out);
}